// Round 1
// baseline (9967.577 us; speedup 1.0000x reference)
//
#include <hip/hip_runtime.h>
#include <math.h>

#define CIN 256
#define COUT 256
#define NB 2
#define GN_GROUPS 16

// ---------------------------------------------------------------------------
// Offset conv: 3x3, 27 output channels, pad 1. One thread per (b, pixel),
// all 27 output channels accumulated in registers. Mask channels (18..26)
// get sigmoid applied at write time.
// ---------------------------------------------------------------------------
__global__ __launch_bounds__(256) void conv_offset_kernel(
    const float* __restrict__ x,      // (B, 256, H, W)
    const float* __restrict__ w,      // (27, 256, 3, 3)
    const float* __restrict__ bias,   // (27,)
    float* __restrict__ om,           // (B, 27, H*W), mask pre-sigmoided
    int H, int W) {
  int P = H * W;
  int idx = blockIdx.x * 256 + threadIdx.x;
  if (idx >= NB * P) return;
  int b = idx / P, p = idx % P;
  int yy = p / W, xx = p % W;

  float acc[27];
#pragma unroll
  for (int o = 0; o < 27; o++) acc[o] = bias[o];

  const float* xb = x + (size_t)b * CIN * P;
  for (int c = 0; c < CIN; c++) {
    const float* xc = xb + (size_t)c * P;
    float v[9];
#pragma unroll
    for (int ky = 0; ky < 3; ky++) {
      int iy = yy + ky - 1;
      bool vy = (iy >= 0 && iy < H);
#pragma unroll
      for (int kx = 0; kx < 3; kx++) {
        int ix = xx + kx - 1;
        v[ky * 3 + kx] = (vy && ix >= 0 && ix < W) ? xc[iy * W + ix] : 0.0f;
      }
    }
    const float* wc = w + c * 9;
#pragma unroll
    for (int o = 0; o < 27; o++) {
      const float* wo = wc + o * (CIN * 9);
#pragma unroll
      for (int k = 0; k < 9; k++) acc[o] += v[k] * wo[k];
    }
  }

  float* omb = om + (size_t)b * 27 * P + p;
#pragma unroll
  for (int o = 0; o < 27; o++) {
    float val = acc[o];
    if (o >= 18) val = 1.0f / (1.0f + __expf(-val));  // sigmoid for mask
    omb[(size_t)o * P] = val;
  }
}

// ---------------------------------------------------------------------------
// Repack conv weight (256, 256, 3, 3) -> (2304, 256): wt[(c*9+k)*256 + oc]
// ---------------------------------------------------------------------------
__global__ void repack_w_kernel(const float* __restrict__ w,
                                float* __restrict__ wt) {
  int idx = blockIdx.x * 256 + threadIdx.x;  // 589824 total
  int oc = idx % 256;
  int kk = idx / 256;
  wt[idx] = w[(size_t)oc * 2304 + kk];
}

// ---------------------------------------------------------------------------
// Modulated deformable conv as implicit GEMM.
// Block: 256 threads; tile = 64 oc x 64 px; per-thread 4x4 fp32 acc.
// K loop over channels in chunks of 8 (72 K values per chunk).
// Sampling metadata (coords + mask-folded bilinear weights, invalid taps
// zeroed) precomputed once per block.
// ---------------------------------------------------------------------------
__global__ __launch_bounds__(256) void mdconv_kernel(
    const float* __restrict__ x, int Hi, int Wi,
    const float* __restrict__ om, int omW, int omP, int omStep,
    const float* __restrict__ wt,   // (2304, 256) repacked
    float* __restrict__ outf,       // (B, 256, Ho*Wo)
    int Ho, int Wo, int stride) {
  __shared__ __align__(16) float s_w4[9][64][4];
  __shared__ int s_yi[9][64];
  __shared__ int s_xi[9][64];
  __shared__ __align__(16) float s_col[72][64];
  __shared__ __align__(16) float s_W[72][64];

  int tid = threadIdx.x;
  int pxt = blockIdx.x, oct = blockIdx.y, b = blockIdx.z;
  int Po = Ho * Wo;

  // Phase 0: sampling metadata for 9 taps x 64 pixels
  for (int e = tid; e < 576; e += 256) {
    int k = e / 64, px = e % 64;
    int p = pxt * 64 + px;
    int i = p / Wo, j = p % Wo;
    int pc = (i * omStep) * omW + j * omStep;
    const float* omb = om + (size_t)b * 27 * omP;
    float offy = omb[(size_t)(2 * k) * omP + pc];
    float offx = omb[(size_t)(2 * k + 1) * omP + pc];
    float m = omb[(size_t)(18 + k) * omP + pc];
    float py = (float)(i * stride) - 1.0f + (float)(k / 3) + offy;
    float pxf = (float)(j * stride) - 1.0f + (float)(k % 3) + offx;
    float y0f = floorf(py), x0f = floorf(pxf);
    float wy = py - y0f, wx = pxf - x0f;
    int y0 = (int)y0f, x0 = (int)x0f;
    int y1 = y0 + 1, x1 = x0 + 1;
    float vy0 = (y0 >= 0 && y0 < Hi) ? 1.0f : 0.0f;
    float vy1 = (y1 >= 0 && y1 < Hi) ? 1.0f : 0.0f;
    float vx0 = (x0 >= 0 && x0 < Wi) ? 1.0f : 0.0f;
    float vx1 = (x1 >= 0 && x1 < Wi) ? 1.0f : 0.0f;
    s_w4[k][px][0] = (1.0f - wy) * (1.0f - wx) * m * vy0 * vx0;
    s_w4[k][px][1] = (1.0f - wy) * wx * m * vy0 * vx1;
    s_w4[k][px][2] = wy * (1.0f - wx) * m * vy1 * vx0;
    s_w4[k][px][3] = wy * wx * m * vy1 * vx1;
    int y0c = min(max(y0, 0), Hi - 1), y1c = min(max(y1, 0), Hi - 1);
    int x0c = min(max(x0, 0), Wi - 1), x1c = min(max(x1, 0), Wi - 1);
    s_yi[k][px] = y0c | (y1c << 16);
    s_xi[k][px] = x0c | (x1c << 16);
  }

  float acc[4][4];
#pragma unroll
  for (int i = 0; i < 4; i++)
#pragma unroll
    for (int j = 0; j < 4; j++) acc[i][j] = 0.0f;

  int pxBase = (tid & 15) * 4;
  int ocBase = (tid >> 4) * 4;
  const float* xb = x + (size_t)b * CIN * Hi * Wi;

  for (int cc = 0; cc < CIN; cc += 8) {
    __syncthreads();  // protect previous iter's reads (and metadata on iter 0)
    // stage weights: s_W[kk][oc]
#pragma unroll
    for (int e = 0; e < 18; e++) {
      int id = tid + e * 256;
      int kk = id / 64, oc = id % 64;
      s_W[kk][oc] = wt[(size_t)(cc * 9 + kk) * 256 + oct * 64 + oc];
    }
    // stage sampled columns: s_col[kk][px]
#pragma unroll
    for (int e = 0; e < 18; e++) {
      int id = tid + e * 256;
      int kk = id / 64, px = id % 64;
      int c = cc + kk / 9, k = kk % 9;
      const float* xc = xb + (size_t)c * Hi * Wi;
      int yy = s_yi[k][px], xx = s_xi[k][px];
      int y0 = yy & 0xffff, y1 = yy >> 16;
      int x0 = xx & 0xffff, x1 = xx >> 16;
      const float4 wv = *(const float4*)&s_w4[k][px][0];
      float v = xc[y0 * Wi + x0] * wv.x + xc[y0 * Wi + x1] * wv.y +
                xc[y1 * Wi + x0] * wv.z + xc[y1 * Wi + x1] * wv.w;
      s_col[kk][px] = v;
    }
    __syncthreads();
    // GEMM on the chunk
#pragma unroll
    for (int kk = 0; kk < 72; kk++) {
      const float4 av = *(const float4*)&s_W[kk][ocBase];
      const float4 bv = *(const float4*)&s_col[kk][pxBase];
      float a[4] = {av.x, av.y, av.z, av.w};
      float bb[4] = {bv.x, bv.y, bv.z, bv.w};
#pragma unroll
      for (int i = 0; i < 4; i++)
#pragma unroll
        for (int j = 0; j < 4; j++) acc[i][j] += a[i] * bb[j];
    }
  }

  float* op = outf + ((size_t)b * COUT + oct * 64 + ocBase) * Po +
              (size_t)pxt * 64 + pxBase;
#pragma unroll
  for (int i = 0; i < 4; i++) {
    float4 v;
    v.x = acc[i][0]; v.y = acc[i][1]; v.z = acc[i][2]; v.w = acc[i][3];
    *(float4*)(op + (size_t)i * Po) = v;
  }
}

// ---------------------------------------------------------------------------
// Per-(b,c) sum and sum-of-squares over P spatial elements.
// Grid: (C, B). Block: 256.
// ---------------------------------------------------------------------------
__global__ __launch_bounds__(256) void chanstats_kernel(
    const float* __restrict__ f, int P,
    float* __restrict__ sum, float* __restrict__ sumsq) {
  int c = blockIdx.x, b = blockIdx.y;
  int tid = threadIdx.x;
  const float* fp = f + ((size_t)b * COUT + c) * P;
  float s = 0.0f, q = 0.0f;
  for (int i = tid; i < P; i += 256) {
    float v = fp[i];
    s += v;
    q += v * v;
  }
#pragma unroll
  for (int off = 32; off > 0; off >>= 1) {
    s += __shfl_down(s, off, 64);
    q += __shfl_down(q, off, 64);
  }
  __shared__ float rs[4], rq[4];
  int lane = tid & 63, wid = tid >> 6;
  if (lane == 0) { rs[wid] = s; rq[wid] = q; }
  __syncthreads();
  if (tid == 0) {
    sum[b * COUT + c] = rs[0] + rs[1] + rs[2] + rs[3];
    sumsq[b * COUT + c] = rq[0] + rq[1] + rq[2] + rq[3];
  }
}

// ---------------------------------------------------------------------------
// GroupNorm prep: per-(b,c) affine A,B from channel sums; per-b attention
// scalar s = hsig(relu(mean(gn_out) . w_sa + b_sa)). Single block of 256.
// ---------------------------------------------------------------------------
__global__ __launch_bounds__(256) void gn_prep_kernel(
    const float* __restrict__ chansum, const float* __restrict__ chansumsq,
    const float* __restrict__ gamma, const float* __restrict__ beta,
    const float* __restrict__ w_sa, const float* __restrict__ b_sa,
    float invP, float invN,
    float* __restrict__ A, float* __restrict__ Bc, float* __restrict__ svec) {
  __shared__ float s_m[NB * GN_GROUPS], s_inv[NB * GN_GROUPS];
  __shared__ float s_contrib[NB * COUT];
  int tid = threadIdx.x;
  if (tid < NB * GN_GROUPS) {
    int b = tid / GN_GROUPS, g = tid % GN_GROUPS;
    float s = 0.0f, q = 0.0f;
    for (int c = g * 16; c < g * 16 + 16; c++) {
      s += chansum[b * COUT + c];
      q += chansumsq[b * COUT + c];
    }
    float m = s * invN;
    float v = q * invN - m * m;
    s_m[tid] = m;
    s_inv[tid] = rsqrtf(v + 1e-5f);
  }
  __syncthreads();
  for (int idx = tid; idx < NB * COUT; idx += 256) {
    int b = idx / COUT, c = idx % COUT, g = c / 16;
    float inv = s_inv[b * GN_GROUPS + g], m = s_m[b * GN_GROUPS + g];
    float a = gamma[c] * inv;
    float bb = beta[c] - m * a;
    A[idx] = a;
    Bc[idx] = bb;
    float p = a * (chansum[idx] * invP) + bb;  // mean of gn output, channel c
    s_contrib[idx] = p * w_sa[c];
  }
  __syncthreads();
  if (tid < NB) {
    float t = 0.0f;
    for (int c = 0; c < COUT; c++) t += s_contrib[tid * COUT + c];
    t += b_sa[0];
    t = fmaxf(t, 0.0f);
    svec[tid] = fminf(fmaxf(t + 3.0f, 0.0f), 6.0f) * (1.0f / 6.0f);
  }
}

// Attention scalar from plain channel means (for resized high path).
__global__ __launch_bounds__(256) void mean_attn_kernel(
    const float* __restrict__ chansum, const float* __restrict__ w_sa,
    const float* __restrict__ b_sa, float invP, float* __restrict__ svec) {
  __shared__ float s_contrib[NB * COUT];
  int tid = threadIdx.x;
  for (int idx = tid; idx < NB * COUT; idx += 256)
    s_contrib[idx] = chansum[idx] * invP * w_sa[idx % COUT];
  __syncthreads();
  if (tid < NB) {
    float t = 0.0f;
    for (int c = 0; c < COUT; c++) t += s_contrib[tid * COUT + c];
    t += b_sa[0];
    t = fmaxf(t, 0.0f);
    svec[tid] = fminf(fmaxf(t + 3.0f, 0.0f), 6.0f) * (1.0f / 6.0f);
  }
}

// out = (f*A + B) * s[b]   (accumulate=0 -> write, 1 -> add)
__global__ __launch_bounds__(256) void apply_gn_kernel(
    const float* __restrict__ f, const float* __restrict__ A,
    const float* __restrict__ Bc, const float* __restrict__ svec,
    float* __restrict__ out, int P, int accumulate) {
  int idx = blockIdx.x * 256 + threadIdx.x;
  int bc = idx / P;
  int b = bc / COUT;
  float v = (f[idx] * A[bc] + Bc[bc]) * svec[b];
  if (accumulate) out[idx] += v;
  else out[idx] = v;
}

// Bilinear align-corners resize with GN affine folded in (affine commutes
// with interpolation). featB[b,c,Y,X] over (Ho,Ho) from f over (Hi,Hi).
__global__ __launch_bounds__(256) void resize_gn_kernel(
    const float* __restrict__ f, const float* __restrict__ A,
    const float* __restrict__ Bc, float* __restrict__ outf, int Hi, int Ho) {
  int idx = blockIdx.x * 256 + threadIdx.x;
  int P = Ho * Ho;
  int bc = idx / P, p = idx % P;
  int Y = p / Ho, X = p % Ho;
  float r = (float)(Hi - 1) / (float)(Ho - 1);
  float sy = (float)Y * r, sx = (float)X * r;
  int yl = (int)floorf(sy), xl = (int)floorf(sx);
  int yh = min(yl + 1, Hi - 1), xh = min(xl + 1, Hi - 1);
  float wy = sy - (float)yl, wx = sx - (float)xl;
  const float* fp = f + (size_t)bc * Hi * Hi;
  float t0 = fp[yl * Hi + xl] * (1.0f - wx) + fp[yl * Hi + xh] * wx;
  float t1 = fp[yh * Hi + xl] * (1.0f - wx) + fp[yh * Hi + xh] * wx;
  float raw = t0 * (1.0f - wy) + t1 * wy;
  outf[idx] = raw * A[bc] + Bc[bc];
}

// out += f * s[b]
__global__ __launch_bounds__(256) void apply_scale_kernel(
    const float* __restrict__ f, const float* __restrict__ svec,
    float* __restrict__ out, int P) {
  int idx = blockIdx.x * 256 + threadIdx.x;
  int b = idx / (COUT * P);
  out[idx] += f[idx] * svec[b];
}

// DyReLU coefficient MLP (tiny, single block).
__global__ __launch_bounds__(256) void dyrelu_prep_kernel(
    const float* __restrict__ chansum, const float* __restrict__ w1,
    const float* __restrict__ b1, const float* __restrict__ w2,
    const float* __restrict__ b2, float invPn, float* __restrict__ coef) {
  __shared__ float s_p[NB * COUT];
  __shared__ float s_h[NB * 64];
  int tid = threadIdx.x;
  for (int idx = tid; idx < NB * COUT; idx += 256)
    s_p[idx] = chansum[idx] * invPn;
  __syncthreads();
  if (tid < NB * 64) {
    int b = tid / 64, j = tid % 64;
    float t = b1[j];
    for (int c = 0; c < COUT; c++) t += s_p[b * COUT + c] * w1[j * COUT + c];
    s_h[tid] = fmaxf(t, 0.0f);
  }
  __syncthreads();
  for (int idx = tid; idx < NB * 1024; idx += 256) {
    int b = idx / 1024, i = idx % 1024;
    float t = b2[i];
    for (int j = 0; j < 64; j++) t += s_h[b * 64 + j] * w2[i * 64 + j];
    float cv = fminf(fmaxf(t + 3.0f, 0.0f), 6.0f) * (1.0f / 6.0f) - 0.5f;
    coef[b * 1024 + i] = cv;  // [b][q][c], q=i/256, c=i%256
  }
}

// out = max(x*a1+b1, x*a2+b2), x = out/n
__global__ __launch_bounds__(256) void dyrelu_apply_kernel(
    float* __restrict__ out, const float* __restrict__ coef, int P,
    float invn) {
  int idx = blockIdx.x * 256 + threadIdx.x;
  int bc = idx / P;
  int b = bc / COUT, c = bc % COUT;
  float x = out[idx] * invn;
  float a1 = coef[b * 1024 + c] * 2.0f + 1.0f;
  float b1v = coef[b * 1024 + 256 + c];
  float a2 = coef[b * 1024 + 512 + c] * 2.0f;
  float b2v = coef[b * 1024 + 768 + c];
  out[idx] = fmaxf(x * a1 + b1v, x * a2 + b2v);
}

// ---------------------------------------------------------------------------
extern "C" void kernel_launch(void* const* d_in, const int* in_sizes, int n_in,
                              void* d_out, int out_size, void* d_ws,
                              size_t ws_size, hipStream_t stream) {
  (void)in_sizes; (void)n_in; (void)out_size; (void)ws_size;
  const float* x[3] = {(const float*)d_in[0], (const float*)d_in[1],
                       (const float*)d_in[2]};
  const float* w_off = (const float*)d_in[3];
  const float* b_off = (const float*)d_in[4];
  const float* w_mid = (const float*)d_in[5];
  const float* g_mid = (const float*)d_in[6];
  const float* be_mid = (const float*)d_in[7];
  const float* w_low = (const float*)d_in[8];
  const float* g_low = (const float*)d_in[9];
  const float* be_low = (const float*)d_in[10];
  const float* w_high = (const float*)d_in[11];
  const float* g_high = (const float*)d_in[12];
  const float* be_high = (const float*)d_in[13];
  const float* w_sa = (const float*)d_in[14];
  const float* b_sa = (const float*)d_in[15];
  const float* w_dy1 = (const float*)d_in[16];
  const float* b_dy1 = (const float*)d_in[17];
  const float* w_dy2 = (const float*)d_in[18];
  const float* b_dy2 = (const float*)d_in[19];

  float* out = (float*)d_out;
  float* ws = (float*)d_ws;

  float* om = ws;                       // 2*27*16384 = 884736
  float* featA = ws + 884736;           // 8388608
  float* featB = featA + 8388608;       // 8388608
  float* wt_mid = featB + 8388608;      // 589824
  float* wt_low = wt_mid + 589824;      // 589824
  float* wt_high = wt_low + 589824;     // 589824
  float* chansum = wt_high + 589824;    // 512
  float* chansumsq = chansum + 512;     // 512
  float* Acoef = chansumsq + 512;       // 512
  float* Bcoef = Acoef + 512;           // 512
  float* svec = Bcoef + 512;            // 64 (padded)
  float* dycoef = svec + 64;            // 2048

  repack_w_kernel<<<2304, 256, 0, stream>>>(w_mid, wt_mid);
  repack_w_kernel<<<2304, 256, 0, stream>>>(w_low, wt_low);
  repack_w_kernel<<<2304, 256, 0, stream>>>(w_high, wt_high);

  const int Hs[3] = {128, 64, 32};
  const size_t outOff[3] = {0, 8388608, 10485760};
  const int nterm[3] = {2, 3, 2};

  for (int l = 0; l < 3; l++) {
    int H = Hs[l];
    int P = H * H;
    float* outl = out + outOff[l];

    conv_offset_kernel<<<(NB * P + 255) / 256, 256, 0, stream>>>(
        x[l], w_off, b_off, om, H, H);

    // ---- mid path ----
    mdconv_kernel<<<dim3(P / 64, 4, NB), 256, 0, stream>>>(
        x[l], H, H, om, H, P, 1, wt_mid, featA, H, H, 1);
    chanstats_kernel<<<dim3(COUT, NB), 256, 0, stream>>>(featA, P, chansum,
                                                         chansumsq);
    gn_prep_kernel<<<1, 256, 0, stream>>>(chansum, chansumsq, g_mid, be_mid,
                                          w_sa, b_sa, 1.0f / P,
                                          1.0f / (16.0f * P), Acoef, Bcoef,
                                          svec);
    apply_gn_kernel<<<(NB * COUT * P) / 256, 256, 0, stream>>>(
        featA, Acoef, Bcoef, svec, outl, P, 0);

    // ---- low path (input level l-1, stride 2) ----
    if (l > 0) {
      int Hi2 = Hs[l - 1];
      mdconv_kernel<<<dim3(P / 64, 4, NB), 256, 0, stream>>>(
          x[l - 1], Hi2, Hi2, om, H, P, 1, wt_low, featA, H, H, 2);
      chanstats_kernel<<<dim3(COUT, NB), 256, 0, stream>>>(featA, P, chansum,
                                                           chansumsq);
      gn_prep_kernel<<<1, 256, 0, stream>>>(chansum, chansumsq, g_low, be_low,
                                            w_sa, b_sa, 1.0f / P,
                                            1.0f / (16.0f * P), Acoef, Bcoef,
                                            svec);
      apply_gn_kernel<<<(NB * COUT * P) / 256, 256, 0, stream>>>(
          featA, Acoef, Bcoef, svec, outl, P, 1);
    }

    // ---- high path (input level l+1, subsampled offsets, then resize) ----
    if (l < 2) {
      int Hh = H / 2;
      int Ph = Hh * Hh;
      mdconv_kernel<<<dim3(Ph / 64, 4, NB), 256, 0, stream>>>(
          x[l + 1], Hh, Hh, om, H, P, 2, wt_high, featA, Hh, Hh, 1);
      chanstats_kernel<<<dim3(COUT, NB), 256, 0, stream>>>(featA, Ph, chansum,
                                                           chansumsq);
      gn_prep_kernel<<<1, 256, 0, stream>>>(chansum, chansumsq, g_high,
                                            be_high, w_sa, b_sa, 1.0f / Ph,
                                            1.0f / (16.0f * Ph), Acoef, Bcoef,
                                            svec);
      resize_gn_kernel<<<(NB * COUT * P) / 256, 256, 0, stream>>>(
          featA, Acoef, Bcoef, featB, Hh, H);
      chanstats_kernel<<<dim3(COUT, NB), 256, 0, stream>>>(featB, P, chansum,
                                                           chansumsq);
      mean_attn_kernel<<<1, 256, 0, stream>>>(chansum, w_sa, b_sa, 1.0f / P,
                                              svec);
      apply_scale_kernel<<<(NB * COUT * P) / 256, 256, 0, stream>>>(
          featB, svec, outl, P);
    }

    // ---- DyReLU ----
    chanstats_kernel<<<dim3(COUT, NB), 256, 0, stream>>>(outl, P, chansum,
                                                         chansumsq);
    dyrelu_prep_kernel<<<1, 256, 0, stream>>>(
        chansum, w_dy1, b_dy1, w_dy2, b_dy2,
        1.0f / ((float)P * (float)nterm[l]), dycoef);
    dyrelu_apply_kernel<<<(NB * COUT * P) / 256, 256, 0, stream>>>(
        outl, dycoef, P, 1.0f / (float)nterm[l]);
  }
}

// Round 2
// 1477.526 us; speedup vs baseline: 6.7461x; 6.7461x over previous
//
#include <hip/hip_runtime.h>
#include <math.h>

#define CIN 256
#define COUT 256
#define NB 2
#define GN_GROUPS 16

typedef __attribute__((ext_vector_type(8))) short short8;
typedef __attribute__((ext_vector_type(4))) float floatx4;

__device__ __forceinline__ float b2f(unsigned short u) {
  union { unsigned int i; float f; } v;
  v.i = ((unsigned int)u) << 16;
  return v.f;
}
__device__ __forceinline__ unsigned short f2b(float f) {
  union { float f; unsigned int i; } v;
  v.f = f;
  unsigned int r = (v.i + 0x7FFFu + ((v.i >> 16) & 1u)) >> 16;
  return (unsigned short)r;
}

// ---------------------------------------------------------------------------
// NCHW fp32 -> NHWC bf16 transpose. grid (P/64, C/64, B), 256 threads.
// ---------------------------------------------------------------------------
__global__ __launch_bounds__(256) void transpose_kernel(
    const float* __restrict__ x, unsigned short* __restrict__ xT, int P) {
  __shared__ float tile[64][65];
  int pBase = blockIdx.x * 64, cBase = blockIdx.y * 64, b = blockIdx.z;
  int t = threadIdx.x;
  int pl = t & 63, ch = t >> 6;
  const float* xb = x + ((size_t)b * CIN + cBase) * P + pBase;
#pragma unroll
  for (int e = 0; e < 16; e++) {
    int c = ch * 16 + e;
    tile[c][pl] = xb[(size_t)c * P + pl];
  }
  __syncthreads();
  unsigned short* xo = xT + ((size_t)b * P + pBase) * CIN + cBase;
  int cl = t & 63, pr = t >> 6;
#pragma unroll
  for (int e = 0; e < 16; e++) {
    int p = pr * 16 + e;
    xo[(size_t)p * CIN + cl] = f2b(tile[cl][p]);
  }
}

// ---------------------------------------------------------------------------
// Repack conv weight (256,256,3,3) fp32 -> bf16 [oc][K], K = tap*256 + c
// ---------------------------------------------------------------------------
__global__ void repack_w_kernel(const float* __restrict__ w,
                                unsigned short* __restrict__ wt) {
  int idx = blockIdx.x * 256 + threadIdx.x;  // 589824
  int oc = idx / 2304, kk = idx % 2304;
  int k = kk >> 8, c = kk & 255;
  wt[idx] = f2b(w[(size_t)oc * 2304 + c * 9 + k]);
}

// ---------------------------------------------------------------------------
// Offset conv (fp32, exact): 3x3, 27 oc. grid (P/64, B), 256 thr = 64px x 4cg.
// Each thread covers 64 channels; weights LDS-staged in 8-ch phases;
// cross-cg reduce via shfl_xor (lanes l, l^1, l^2 share the pixel).
// ---------------------------------------------------------------------------
__global__ __launch_bounds__(256) void conv_offset_kernel(
    const float* __restrict__ x, const float* __restrict__ w,
    const float* __restrict__ bias, float* __restrict__ om, int H, int W) {
  __shared__ float s_w[32 * 243];
  int P = H * W;
  int t = threadIdx.x;
  int pxl = t >> 2, cg = t & 3;
  int b = blockIdx.y;
  int p = blockIdx.x * 64 + pxl;
  int yy = p / W, xx = p % W;
  float acc[27];
#pragma unroll
  for (int o = 0; o < 27; o++) acc[o] = 0.f;
  const float* xb = x + (size_t)b * CIN * P;

  for (int ph = 0; ph < 8; ph++) {
    __syncthreads();
    for (int e = t; e < 32 * 243; e += 256) {
      int cc = e / 243, rest = e % 243;
      int o = rest / 9, k = rest % 9;
      int c = (cc >> 3) * 64 + ph * 8 + (cc & 7);
      s_w[e] = w[(size_t)o * 2304 + c * 9 + k];
    }
    __syncthreads();
    for (int c8 = 0; c8 < 8; c8++) {
      int c = cg * 64 + ph * 8 + c8;
      const float* xc = xb + (size_t)c * P;
      float v[9];
#pragma unroll
      for (int ky = 0; ky < 3; ky++) {
        int iy = yy + ky - 1;
        bool vy = (iy >= 0 && iy < H);
#pragma unroll
        for (int kx = 0; kx < 3; kx++) {
          int ix = xx + kx - 1;
          v[ky * 3 + kx] = (vy && ix >= 0 && ix < W) ? xc[iy * W + ix] : 0.f;
        }
      }
      const float* wl = &s_w[(cg * 8 + c8) * 243];
#pragma unroll
      for (int o = 0; o < 27; o++) {
#pragma unroll
        for (int k = 0; k < 9; k++) acc[o] += v[k] * wl[o * 9 + k];
      }
    }
  }
#pragma unroll
  for (int o = 0; o < 27; o++) {
    float s = acc[o];
    s += __shfl_xor(s, 1, 64);
    s += __shfl_xor(s, 2, 64);
    acc[o] = s;
  }
  if (cg == 0) {
    float* omb = om + (size_t)b * 27 * P + p;
#pragma unroll
    for (int o = 0; o < 27; o++) {
      float val = acc[o] + bias[o];
      if (o >= 18) val = 1.f / (1.f + __expf(-val));
      omb[(size_t)o * P] = val;
    }
  }
}

// ---------------------------------------------------------------------------
// Modulated deformable conv, bf16 MFMA implicit GEMM.
// Block: 256 thr (4 waves). Tile: 64 px x 256 oc (wave w: oc [64w,64w+64)).
// K = 2304 ordered tap-major (K = tap*256 + c); chunks of 32 (one tap, 32 ch).
// Gather from NHWC bf16 xT: per (px, 4ch) item load 4 corner ushort4s
// (coalesced), combine with mask-folded bilinear weights, store bf16 col tile.
// ---------------------------------------------------------------------------
__global__ __launch_bounds__(256) void mdconv_kernel(
    const unsigned short* __restrict__ xT, int Hi, int Wi,
    const float* __restrict__ om, int omW, int omP, int omStep,
    const unsigned short* __restrict__ wtT,  // [256][2304] bf16
    float* __restrict__ outf, int Ho, int Wo, int stride) {
  __shared__ float4 s_cw[9][64];
  __shared__ int s_yy[9][64];
  __shared__ int s_xx[9][64];
  __shared__ unsigned short s_wA[256][40];   // 32 K + pad, 80B row (16B align)
  __shared__ unsigned short s_colT[64][40];

  int t = threadIdx.x;
  int pxt = blockIdx.x, b = blockIdx.y;
  int Po = Ho * Wo;
  const unsigned short* xTb = xT + (size_t)b * Hi * Wi * CIN;

  // Phase 0: sampling metadata for 9 taps x 64 px
  for (int e = t; e < 576; e += 256) {
    int k = e / 64, px = e % 64;
    int p = pxt * 64 + px;
    int i = p / Wo, j = p % Wo;
    int pc = (i * omStep) * omW + j * omStep;
    const float* omb = om + (size_t)b * 27 * omP;
    float offy = omb[(size_t)(2 * k) * omP + pc];
    float offx = omb[(size_t)(2 * k + 1) * omP + pc];
    float m = omb[(size_t)(18 + k) * omP + pc];
    float py = (float)(i * stride) - 1.0f + (float)(k / 3) + offy;
    float pxf = (float)(j * stride) - 1.0f + (float)(k % 3) + offx;
    float y0f = floorf(py), x0f = floorf(pxf);
    float wy = py - y0f, wx = pxf - x0f;
    int y0 = (int)y0f, x0 = (int)x0f;
    int y1 = y0 + 1, x1 = x0 + 1;
    float vy0 = (y0 >= 0 && y0 < Hi) ? 1.f : 0.f;
    float vy1 = (y1 >= 0 && y1 < Hi) ? 1.f : 0.f;
    float vx0 = (x0 >= 0 && x0 < Wi) ? 1.f : 0.f;
    float vx1 = (x1 >= 0 && x1 < Wi) ? 1.f : 0.f;
    float4 cw;
    cw.x = (1.f - wy) * (1.f - wx) * m * vy0 * vx0;
    cw.y = (1.f - wy) * wx * m * vy0 * vx1;
    cw.z = wy * (1.f - wx) * m * vy1 * vx0;
    cw.w = wy * wx * m * vy1 * vx1;
    s_cw[k][px] = cw;
    int y0c = min(max(y0, 0), Hi - 1), y1c = min(max(y1, 0), Hi - 1);
    int x0c = min(max(x0, 0), Wi - 1), x1c = min(max(x1, 0), Wi - 1);
    s_yy[k][px] = y0c | (y1c << 16);
    s_xx[k][px] = x0c | (x1c << 16);
  }

  floatx4 acc[4][4];
#pragma unroll
  for (int i = 0; i < 4; i++)
#pragma unroll
    for (int j = 0; j < 4; j++) acc[i][j] = (floatx4){0.f, 0.f, 0.f, 0.f};

  int lane = t & 63, wv = t >> 6;
  int quad = lane >> 4, ln = lane & 15;
  int wOc = wv * 64;

  for (int kc = 0; kc < 72; kc++) {
    int k = kc >> 3, cb = kc & 7;
    int kBase = k * 256 + cb * 32;
    __syncthreads();
    // stage weight tile: 256 oc x 32 K
#pragma unroll
    for (int e = 0; e < 4; e++) {
      int id = e * 256 + t;
      int oc = id >> 2, part = id & 3;
      *(short8*)&s_wA[oc][part * 8] =
          *(const short8*)(wtT + (size_t)oc * 2304 + kBase + part * 8);
    }
    // stage col tile: 64 px x 32 ch (this tap)
#pragma unroll
    for (int phs = 0; phs < 2; phs++) {
      int id = phs * 256 + t;
      int px = id >> 3, q = id & 7;
      int c4 = cb * 32 + q * 4;
      float4 cw = s_cw[k][px];
      int yy = s_yy[k][px], xx = s_xx[k][px];
      int y0 = yy & 0xffff, y1 = (yy >> 16) & 0xffff;
      int x0 = xx & 0xffff, x1 = (xx >> 16) & 0xffff;
      const unsigned short* base = xTb + c4;
      ushort4 v00 = *(const ushort4*)(base + (y0 * Wi + x0) * CIN);
      ushort4 v01 = *(const ushort4*)(base + (y0 * Wi + x1) * CIN);
      ushort4 v10 = *(const ushort4*)(base + (y1 * Wi + x0) * CIN);
      ushort4 v11 = *(const ushort4*)(base + (y1 * Wi + x1) * CIN);
      ushort4 r;
      r.x = f2b(cw.x * b2f(v00.x) + cw.y * b2f(v01.x) + cw.z * b2f(v10.x) +
                cw.w * b2f(v11.x));
      r.y = f2b(cw.x * b2f(v00.y) + cw.y * b2f(v01.y) + cw.z * b2f(v10.y) +
                cw.w * b2f(v11.y));
      r.z = f2b(cw.x * b2f(v00.z) + cw.y * b2f(v01.z) + cw.z * b2f(v10.z) +
                cw.w * b2f(v11.z));
      r.w = f2b(cw.x * b2f(v00.w) + cw.y * b2f(v01.w) + cw.z * b2f(v10.w) +
                cw.w * b2f(v11.w));
      *(ushort4*)&s_colT[px][q * 4] = r;
    }
    __syncthreads();
    short8 af[4], bfr[4];
#pragma unroll
    for (int i = 0; i < 4; i++)
      af[i] = *(const short8*)&s_wA[wOc + i * 16 + ln][quad * 8];
#pragma unroll
    for (int j = 0; j < 4; j++)
      bfr[j] = *(const short8*)&s_colT[j * 16 + ln][quad * 8];
#pragma unroll
    for (int i = 0; i < 4; i++)
#pragma unroll
      for (int j = 0; j < 4; j++)
        acc[i][j] = __builtin_amdgcn_mfma_f32_16x16x32_bf16(af[i], bfr[j],
                                                            acc[i][j], 0, 0, 0);
  }

  // epilogue: C/D layout col=lane&15 (px), row=(lane>>4)*4+reg (oc)
#pragma unroll
  for (int i = 0; i < 4; i++) {
    int ocB = wOc + i * 16 + quad * 4;
#pragma unroll
    for (int j = 0; j < 4; j++) {
      int px = pxt * 64 + j * 16 + ln;
#pragma unroll
      for (int r = 0; r < 4; r++)
        outf[((size_t)b * COUT + ocB + r) * Po + px] = acc[i][j][r];
    }
  }
}

// ---------------------------------------------------------------------------
// Per-(b,c) sum / sum-of-squares. Grid (C, B), 256 thr.
// ---------------------------------------------------------------------------
__global__ __launch_bounds__(256) void chanstats_kernel(
    const float* __restrict__ f, int P, float* __restrict__ sum,
    float* __restrict__ sumsq) {
  int c = blockIdx.x, b = blockIdx.y;
  int tid = threadIdx.x;
  const float* fp = f + ((size_t)b * COUT + c) * P;
  float s = 0.0f, q = 0.0f;
  for (int i = tid; i < P; i += 256) {
    float v = fp[i];
    s += v;
    q += v * v;
  }
#pragma unroll
  for (int off = 32; off > 0; off >>= 1) {
    s += __shfl_down(s, off, 64);
    q += __shfl_down(q, off, 64);
  }
  __shared__ float rs[4], rq[4];
  int lane = tid & 63, wid = tid >> 6;
  if (lane == 0) { rs[wid] = s; rq[wid] = q; }
  __syncthreads();
  if (tid == 0) {
    sum[b * COUT + c] = rs[0] + rs[1] + rs[2] + rs[3];
    sumsq[b * COUT + c] = rq[0] + rq[1] + rq[2] + rq[3];
  }
}

// ---------------------------------------------------------------------------
// GN affine (A,B) + attention scalar from gn-output channel means.
// ---------------------------------------------------------------------------
__global__ __launch_bounds__(256) void gn_prep_kernel(
    const float* __restrict__ chansum, const float* __restrict__ chansumsq,
    const float* __restrict__ gamma, const float* __restrict__ beta,
    const float* __restrict__ w_sa, const float* __restrict__ b_sa, float invP,
    float invN, float* __restrict__ A, float* __restrict__ Bc,
    float* __restrict__ svec) {
  __shared__ float s_m[NB * GN_GROUPS], s_inv[NB * GN_GROUPS];
  __shared__ float s_contrib[NB * COUT];
  int tid = threadIdx.x;
  if (tid < NB * GN_GROUPS) {
    int b = tid / GN_GROUPS, g = tid % GN_GROUPS;
    float s = 0.0f, q = 0.0f;
    for (int c = g * 16; c < g * 16 + 16; c++) {
      s += chansum[b * COUT + c];
      q += chansumsq[b * COUT + c];
    }
    float m = s * invN;
    float v = q * invN - m * m;
    s_m[tid] = m;
    s_inv[tid] = rsqrtf(v + 1e-5f);
  }
  __syncthreads();
  for (int idx = tid; idx < NB * COUT; idx += 256) {
    int b = idx / COUT, c = idx % COUT, g = c / 16;
    float inv = s_inv[b * GN_GROUPS + g], m = s_m[b * GN_GROUPS + g];
    float a = gamma[c] * inv;
    float bb = beta[c] - m * a;
    A[idx] = a;
    Bc[idx] = bb;
    float p = a * (chansum[idx] * invP) + bb;
    s_contrib[idx] = p * w_sa[c];
  }
  __syncthreads();
  if (tid < NB) {
    float t = 0.0f;
    for (int c = 0; c < COUT; c++) t += s_contrib[tid * COUT + c];
    t += b_sa[0];
    t = fmaxf(t, 0.0f);
    svec[tid] = fminf(fmaxf(t + 3.0f, 0.0f), 6.0f) * (1.0f / 6.0f);
  }
}

// out = (f*A + B) * s[b]   (accumulate=0 write, 1 add)
__global__ __launch_bounds__(256) void apply_gn_kernel(
    const float* __restrict__ f, const float* __restrict__ A,
    const float* __restrict__ Bc, const float* __restrict__ svec,
    float* __restrict__ out, int P, int accumulate) {
  int idx = blockIdx.x * 256 + threadIdx.x;
  int bc = idx / P;
  int b = bc / COUT;
  float v = (f[idx] * A[bc] + Bc[bc]) * svec[b];
  if (accumulate) out[idx] += v;
  else out[idx] = v;
}

// Resize weight profile: wprof[i] = sum_Y weight(Y -> i), align-corners.
__global__ void wprofile_kernel(float* __restrict__ wprof, int Hi, int Ho) {
  __shared__ float s_w[64];
  int t = threadIdx.x;
  if (t < Hi) s_w[t] = 0.f;
  __syncthreads();
  if (t < Ho) {
    float r = (float)(Hi - 1) / (float)(Ho - 1);
    float sy = (float)t * r;
    int yl = (int)floorf(sy);
    float fy = sy - (float)yl;
    int yh = min(yl + 1, Hi - 1);
    atomicAdd(&s_w[yl], 1.f - fy);
    atomicAdd(&s_w[yh], fy);
  }
  __syncthreads();
  if (t < Hi) wprof[t] = s_w[t];
}

// Weighted channel sum: S_w[b][c] = sum_p f * wprof[i] * wprof[j]
__global__ __launch_bounds__(256) void wchanstats_kernel(
    const float* __restrict__ f, int P, int Wd,
    const float* __restrict__ wprof, float* __restrict__ swsum) {
  int c = blockIdx.x, b = blockIdx.y;
  int tid = threadIdx.x;
  const float* fp = f + ((size_t)b * COUT + c) * P;
  float s = 0.0f;
  for (int p = tid; p < P; p += 256) {
    int i = p / Wd, j = p % Wd;
    s += fp[p] * wprof[i] * wprof[j];
  }
#pragma unroll
  for (int off = 32; off > 0; off >>= 1) s += __shfl_down(s, off, 64);
  __shared__ float rs[4];
  int lane = tid & 63, wid = tid >> 6;
  if (lane == 0) rs[wid] = s;
  __syncthreads();
  if (tid == 0) swsum[b * COUT + c] = rs[0] + rs[1] + rs[2] + rs[3];
}

// Attention scalar of the resized gn output: mean = A*S_w/P + B.
__global__ __launch_bounds__(256) void attn_wsum_kernel(
    const float* __restrict__ swsum, const float* __restrict__ A,
    const float* __restrict__ Bc, const float* __restrict__ w_sa,
    const float* __restrict__ b_sa, float invP, float* __restrict__ svec) {
  __shared__ float s_contrib[NB * COUT];
  int t = threadIdx.x;
  for (int idx = t; idx < NB * COUT; idx += 256) {
    float mean = A[idx] * swsum[idx] * invP + Bc[idx];
    s_contrib[idx] = mean * w_sa[idx % COUT];
  }
  __syncthreads();
  if (t < NB) {
    float tt = 0.f;
    for (int c = 0; c < COUT; c++) tt += s_contrib[t * COUT + c];
    tt += b_sa[0];
    tt = fmaxf(tt, 0.f);
    svec[t] = fminf(fmaxf(tt + 3.f, 0.f), 6.f) * (1.0f / 6.0f);
  }
}

// out += resize(f)*A*s + B*s  (GN affine commutes with bilinear resize)
__global__ __launch_bounds__(256) void resize_apply_kernel(
    const float* __restrict__ f, const float* __restrict__ A,
    const float* __restrict__ Bc, const float* __restrict__ svec,
    float* __restrict__ out, int Hi, int Ho) {
  int idx = blockIdx.x * 256 + threadIdx.x;
  int P = Ho * Ho;
  int bc = idx / P, p = idx % P;
  int Y = p / Ho, X = p % Ho;
  float r = (float)(Hi - 1) / (float)(Ho - 1);
  float sy = (float)Y * r, sx = (float)X * r;
  int yl = (int)floorf(sy), xl = (int)floorf(sx);
  int yh = min(yl + 1, Hi - 1), xh = min(xl + 1, Hi - 1);
  float wy = sy - (float)yl, wx = sx - (float)xl;
  const float* fp = f + (size_t)bc * Hi * Hi;
  float t0 = fp[yl * Hi + xl] * (1.f - wx) + fp[yl * Hi + xh] * wx;
  float t1 = fp[yh * Hi + xl] * (1.f - wx) + fp[yh * Hi + xh] * wx;
  int b = bc / COUT;
  out[idx] += ((t0 * (1.f - wy) + t1 * wy) * A[bc] + Bc[bc]) * svec[b];
}

// DyReLU coefficient MLP (tiny, single block).
__global__ __launch_bounds__(256) void dyrelu_prep_kernel(
    const float* __restrict__ chansum, const float* __restrict__ w1,
    const float* __restrict__ b1, const float* __restrict__ w2,
    const float* __restrict__ b2, float invPn, float* __restrict__ coef) {
  __shared__ float s_p[NB * COUT];
  __shared__ float s_h[NB * 64];
  int tid = threadIdx.x;
  for (int idx = tid; idx < NB * COUT; idx += 256)
    s_p[idx] = chansum[idx] * invPn;
  __syncthreads();
  if (tid < NB * 64) {
    int b = tid / 64, j = tid % 64;
    float t = b1[j];
    for (int c = 0; c < COUT; c++) t += s_p[b * COUT + c] * w1[j * COUT + c];
    s_h[tid] = fmaxf(t, 0.0f);
  }
  __syncthreads();
  for (int idx = tid; idx < NB * 1024; idx += 256) {
    int b = idx / 1024, i = idx % 1024;
    float t = b2[i];
    for (int j = 0; j < 64; j++) t += s_h[b * 64 + j] * w2[i * 64 + j];
    float cv = fminf(fmaxf(t + 3.0f, 0.0f), 6.0f) * (1.0f / 6.0f) - 0.5f;
    coef[b * 1024 + i] = cv;
  }
}

__global__ __launch_bounds__(256) void dyrelu_apply_kernel(
    float* __restrict__ out, const float* __restrict__ coef, int P,
    float invn) {
  int idx = blockIdx.x * 256 + threadIdx.x;
  int bc = idx / P;
  int b = bc / COUT, c = bc % COUT;
  float x = out[idx] * invn;
  float a1 = coef[b * 1024 + c] * 2.0f + 1.0f;
  float b1v = coef[b * 1024 + 256 + c];
  float a2 = coef[b * 1024 + 512 + c] * 2.0f;
  float b2v = coef[b * 1024 + 768 + c];
  out[idx] = fmaxf(x * a1 + b1v, x * a2 + b2v);
}

// ---------------------------------------------------------------------------
extern "C" void kernel_launch(void* const* d_in, const int* in_sizes, int n_in,
                              void* d_out, int out_size, void* d_ws,
                              size_t ws_size, hipStream_t stream) {
  (void)in_sizes; (void)n_in; (void)out_size; (void)ws_size;
  const float* x[3] = {(const float*)d_in[0], (const float*)d_in[1],
                       (const float*)d_in[2]};
  const float* w_off = (const float*)d_in[3];
  const float* b_off = (const float*)d_in[4];
  const float* w_mid = (const float*)d_in[5];
  const float* g_mid = (const float*)d_in[6];
  const float* be_mid = (const float*)d_in[7];
  const float* w_low = (const float*)d_in[8];
  const float* g_low = (const float*)d_in[9];
  const float* be_low = (const float*)d_in[10];
  const float* w_high = (const float*)d_in[11];
  const float* g_high = (const float*)d_in[12];
  const float* be_high = (const float*)d_in[13];
  const float* w_sa = (const float*)d_in[14];
  const float* b_sa = (const float*)d_in[15];
  const float* w_dy1 = (const float*)d_in[16];
  const float* b_dy1 = (const float*)d_in[17];
  const float* w_dy2 = (const float*)d_in[18];
  const float* b_dy2 = (const float*)d_in[19];

  float* out = (float*)d_out;
  unsigned char* wsb = (unsigned char*)d_ws;

  unsigned short* xT0 = (unsigned short*)wsb;     // 8388608
  unsigned short* xT1 = xT0 + 8388608;            // 2097152
  unsigned short* xT2 = xT1 + 2097152;            // 524288
  unsigned short* wtm = xT2 + 524288;             // 589824
  unsigned short* wtl = wtm + 589824;
  unsigned short* wth = wtl + 589824;
  float* om = (float*)(wsb + 25559040);           // 884736 floats
  float* featA = om + 884736;                     // 8388608
  float* chansum = featA + 8388608;               // 512
  float* chansumsq = chansum + 512;               // 512
  float* Acoef = chansumsq + 512;                 // 512
  float* Bcoef = Acoef + 512;                     // 512
  float* svec = Bcoef + 512;                      // 64
  float* dycoef = svec + 64;                      // 2048
  float* wprof = dycoef + 2048;                   // 64
  float* Swsum = wprof + 64;                      // 512

  const unsigned short* xT[3] = {xT0, xT1, xT2};

  transpose_kernel<<<dim3(256, 4, NB), 256, 0, stream>>>(x[0], xT0, 16384);
  transpose_kernel<<<dim3(64, 4, NB), 256, 0, stream>>>(x[1], xT1, 4096);
  transpose_kernel<<<dim3(16, 4, NB), 256, 0, stream>>>(x[2], xT2, 1024);
  repack_w_kernel<<<2304, 256, 0, stream>>>(w_mid, wtm);
  repack_w_kernel<<<2304, 256, 0, stream>>>(w_low, wtl);
  repack_w_kernel<<<2304, 256, 0, stream>>>(w_high, wth);

  const int Hs[3] = {128, 64, 32};
  const size_t outOff[3] = {0, 8388608, 10485760};
  const int nterm[3] = {2, 3, 2};

  for (int l = 0; l < 3; l++) {
    int H = Hs[l];
    int P = H * H;
    float* outl = out + outOff[l];

    conv_offset_kernel<<<dim3(P / 64, NB), 256, 0, stream>>>(x[l], w_off,
                                                             b_off, om, H, H);

    // ---- mid path ----
    mdconv_kernel<<<dim3(P / 64, NB), 256, 0, stream>>>(
        xT[l], H, H, om, H, P, 1, wtm, featA, H, H, 1);
    chanstats_kernel<<<dim3(COUT, NB), 256, 0, stream>>>(featA, P, chansum,
                                                         chansumsq);
    gn_prep_kernel<<<1, 256, 0, stream>>>(chansum, chansumsq, g_mid, be_mid,
                                          w_sa, b_sa, 1.0f / P,
                                          1.0f / (16.0f * P), Acoef, Bcoef,
                                          svec);
    apply_gn_kernel<<<(NB * COUT * P) / 256, 256, 0, stream>>>(
        featA, Acoef, Bcoef, svec, outl, P, 0);

    // ---- low path (input level l-1, stride 2) ----
    if (l > 0) {
      int Hp = Hs[l - 1];
      mdconv_kernel<<<dim3(P / 64, NB), 256, 0, stream>>>(
          xT[l - 1], Hp, Hp, om, H, P, 1, wtl, featA, H, H, 2);
      chanstats_kernel<<<dim3(COUT, NB), 256, 0, stream>>>(featA, P, chansum,
                                                           chansumsq);
      gn_prep_kernel<<<1, 256, 0, stream>>>(chansum, chansumsq, g_low, be_low,
                                            w_sa, b_sa, 1.0f / P,
                                            1.0f / (16.0f * P), Acoef, Bcoef,
                                            svec);
      apply_gn_kernel<<<(NB * COUT * P) / 256, 256, 0, stream>>>(
          featA, Acoef, Bcoef, svec, outl, P, 1);
    }

    // ---- high path (input level l+1, subsampled offsets, fused resize) ----
    if (l < 2) {
      int Hh = H / 2;
      int Ph = Hh * Hh;
      mdconv_kernel<<<dim3(Ph / 64, NB), 256, 0, stream>>>(
          xT[l + 1], Hh, Hh, om, H, P, 2, wth, featA, Hh, Hh, 1);
      chanstats_kernel<<<dim3(COUT, NB), 256, 0, stream>>>(featA, Ph, chansum,
                                                           chansumsq);
      gn_prep_kernel<<<1, 256, 0, stream>>>(chansum, chansumsq, g_high,
                                            be_high, w_sa, b_sa, 1.0f / Ph,
                                            1.0f / (16.0f * Ph), Acoef, Bcoef,
                                            svec);
      wprofile_kernel<<<1, 128, 0, stream>>>(wprof, Hh, H);
      wchanstats_kernel<<<dim3(COUT, NB), 256, 0, stream>>>(featA, Ph, Hh,
                                                            wprof, Swsum);
      attn_wsum_kernel<<<1, 256, 0, stream>>>(Swsum, Acoef, Bcoef, w_sa, b_sa,
                                              1.0f / P, svec);
      resize_apply_kernel<<<(NB * COUT * P) / 256, 256, 0, stream>>>(
          featA, Acoef, Bcoef, svec, outl, Hh, H);
    }

    // ---- DyReLU ----
    chanstats_kernel<<<dim3(COUT, NB), 256, 0, stream>>>(outl, P, chansum,
                                                         chansumsq);
    dyrelu_prep_kernel<<<1, 256, 0, stream>>>(
        chansum, w_dy1, b_dy1, w_dy2, b_dy2,
        1.0f / ((float)P * (float)nterm[l]), dycoef);
    dyrelu_apply_kernel<<<(NB * COUT * P) / 256, 256, 0, stream>>>(
        outl, dycoef, P, 1.0f / (float)nterm[l]);
  }
}

// Round 3
// 1417.127 us; speedup vs baseline: 7.0337x; 1.0426x over previous
//
#include <hip/hip_runtime.h>
#include <math.h>

#define CIN 256
#define COUT 256
#define NB 2
#define GN_GROUPS 16

typedef __attribute__((ext_vector_type(8))) short short8;
typedef __attribute__((ext_vector_type(4))) float floatx4;

__device__ __forceinline__ float b2f(unsigned short u) {
  union { unsigned int i; float f; } v;
  v.i = ((unsigned int)u) << 16;
  return v.f;
}
__device__ __forceinline__ unsigned short f2b(float f) {
  union { float f; unsigned int i; } v;
  v.f = f;
  unsigned int r = (v.i + 0x7FFFu + ((v.i >> 16) & 1u)) >> 16;
  return (unsigned short)r;
}

// ---------------------------------------------------------------------------
// NCHW fp32 -> NHWC bf16 (hi, round-to-nearest-even). grid (P/64, C/64, B).
// ---------------------------------------------------------------------------
__global__ __launch_bounds__(256) void transpose_kernel(
    const float* __restrict__ x, unsigned short* __restrict__ xT, int P) {
  __shared__ float tile[64][65];
  int pBase = blockIdx.x * 64, cBase = blockIdx.y * 64, b = blockIdx.z;
  int t = threadIdx.x;
  int pl = t & 63, ch = t >> 6;
  const float* xb = x + ((size_t)b * CIN + cBase) * P + pBase;
#pragma unroll
  for (int e = 0; e < 16; e++) {
    int c = ch * 16 + e;
    tile[c][pl] = xb[(size_t)c * P + pl];
  }
  __syncthreads();
  unsigned short* xo = xT + ((size_t)b * P + pBase) * CIN + cBase;
  int cl = t & 63, pr = t >> 6;
#pragma unroll
  for (int e = 0; e < 16; e++) {
    int p = pr * 16 + e;
    xo[(size_t)p * CIN + cl] = f2b(tile[cl][p]);
  }
}

// Same, but writes the bf16 residual lo = x - b2f(f2b(x)).
__global__ __launch_bounds__(256) void transpose_lo_kernel(
    const float* __restrict__ x, unsigned short* __restrict__ xLo, int P) {
  __shared__ float tile[64][65];
  int pBase = blockIdx.x * 64, cBase = blockIdx.y * 64, b = blockIdx.z;
  int t = threadIdx.x;
  int pl = t & 63, ch = t >> 6;
  const float* xb = x + ((size_t)b * CIN + cBase) * P + pBase;
#pragma unroll
  for (int e = 0; e < 16; e++) {
    int c = ch * 16 + e;
    tile[c][pl] = xb[(size_t)c * P + pl];
  }
  __syncthreads();
  unsigned short* xo = xLo + ((size_t)b * P + pBase) * CIN + cBase;
  int cl = t & 63, pr = t >> 6;
#pragma unroll
  for (int e = 0; e < 16; e++) {
    int p = pr * 16 + e;
    float v = tile[cl][p];
    float hi = b2f(f2b(v));
    xo[(size_t)p * CIN + cl] = f2b(v - hi);
  }
}

// ---------------------------------------------------------------------------
// Repack mdconv weight (256,256,3,3) fp32 -> bf16 [oc][K], K = tap*256 + c
// ---------------------------------------------------------------------------
__global__ void repack_w_kernel(const float* __restrict__ w,
                                unsigned short* __restrict__ wt) {
  int idx = blockIdx.x * 256 + threadIdx.x;  // 589824
  int oc = idx / 2304, kk = idx % 2304;
  int k = kk >> 8, c = kk & 255;
  wt[idx] = f2b(w[(size_t)oc * 2304 + c * 9 + k]);
}

// ---------------------------------------------------------------------------
// Repack offset-conv weight (27,256,3,3) -> bf16 hi/lo
// wo[sel][tap 9][cb 8][oc 32][ch 32], oc 27..31 zero.  147456 elems.
// ---------------------------------------------------------------------------
__global__ void repack_wo_kernel(const float* __restrict__ w,
                                 unsigned short* __restrict__ wo) {
  int idx = blockIdx.x * 256 + threadIdx.x;  // 2*73728
  int sel = idx / 73728;
  int r = idx % 73728;
  int k = r / 8192;
  int r2 = r % 8192;
  int cb = r2 / 1024;
  int oc = (r2 / 32) % 32;
  int ch = r2 % 32;
  int c = cb * 32 + ch;
  float val = (oc < 27) ? w[(size_t)oc * 2304 + c * 9 + k] : 0.0f;
  float hi = b2f(f2b(val));
  wo[idx] = sel ? f2b(val - hi) : f2b(val);
}

// ---------------------------------------------------------------------------
// Offset conv via MFMA, split-bf16 (x_hi*w_hi + x_hi*w_lo + x_lo*w_hi).
// Block 256 thr, tile 64 px x 32 oc (27 used). grid (P/64, B).
// ---------------------------------------------------------------------------
__global__ __launch_bounds__(256) void conv_offset_mfma_kernel(
    const unsigned short* __restrict__ xhi, const unsigned short* __restrict__ xlo,
    const unsigned short* __restrict__ wo, const float* __restrict__ bias,
    float* __restrict__ om, int H, int W, int lw) {
  __shared__ unsigned short s_w[32][40];
  __shared__ unsigned short s_col[64][40];
  int t = threadIdx.x;
  int P = H * W;
  int pxt = blockIdx.x, b = blockIdx.y;
  int lane = t & 63, wv = t >> 6;
  int quad = lane >> 4, ln = lane & 15;

  const unsigned short* xhib = xhi + (size_t)b * P * CIN;
  const unsigned short* xlob = xlo + (size_t)b * P * CIN;

  floatx4 acc[2];
  acc[0] = (floatx4){0.f, 0.f, 0.f, 0.f};
  acc[1] = (floatx4){0.f, 0.f, 0.f, 0.f};

  for (int ci = 0; ci < 216; ci++) {
    int seg = ci / 72;
    int rr = ci % 72;
    int k = rr >> 3, cb = rr & 7;
    const unsigned short* xs = (seg == 2) ? xlob : xhib;
    int wsel = (seg == 1) ? 1 : 0;
    int dy = k / 3 - 1, dx = k % 3 - 1;
    __syncthreads();
    {
      int oc = t >> 3, q = t & 7;
      *(ushort4*)&s_w[oc][q * 4] = *(const ushort4*)(
          wo + ((((size_t)wsel * 9 + k) * 8 + cb) * 32 + oc) * 32 + q * 4);
    }
#pragma unroll
    for (int it = 0; it < 2; it++) {
      int id = it * 256 + t;
      int px = id >> 3, q = id & 7;
      int p = pxt * 64 + px;
      int i = p >> lw, j = p & (W - 1);
      int iy = i + dy, ix = j + dx;
      ushort4 val = {0, 0, 0, 0};
      if (iy >= 0 && iy < H && ix >= 0 && ix < W)
        val = *(const ushort4*)(xs + ((size_t)(iy * W + ix)) * CIN + cb * 32 +
                                q * 4);
      *(ushort4*)&s_col[px][q * 4] = val;
    }
    __syncthreads();
    short8 af0 = *(const short8*)&s_w[ln][quad * 8];
    short8 af1 = *(const short8*)&s_w[16 + ln][quad * 8];
    short8 bfr = *(const short8*)&s_col[wv * 16 + ln][quad * 8];
    acc[0] = __builtin_amdgcn_mfma_f32_16x16x32_bf16(af0, bfr, acc[0], 0, 0, 0);
    acc[1] = __builtin_amdgcn_mfma_f32_16x16x32_bf16(af1, bfr, acc[1], 0, 0, 0);
  }

#pragma unroll
  for (int i2 = 0; i2 < 2; i2++) {
#pragma unroll
    for (int r = 0; r < 4; r++) {
      int oc = i2 * 16 + quad * 4 + r;
      if (oc < 27) {
        float val = acc[i2][r] + bias[oc];
        if (oc >= 18) val = 1.f / (1.f + __expf(-val));
        om[((size_t)b * 27 + oc) * P + pxt * 64 + wv * 16 + ln] = val;
      }
    }
  }
}

// ---------------------------------------------------------------------------
// Modulated deformable conv, bf16 MFMA implicit GEMM (unchanged from r2).
// ---------------------------------------------------------------------------
__global__ __launch_bounds__(256) void mdconv_kernel(
    const unsigned short* __restrict__ xT, int Hi, int Wi,
    const float* __restrict__ om, int omW, int omP, int omStep,
    const unsigned short* __restrict__ wtT, float* __restrict__ outf, int Ho,
    int Wo, int stride) {
  __shared__ float4 s_cw[9][64];
  __shared__ int s_yy[9][64];
  __shared__ int s_xx[9][64];
  __shared__ unsigned short s_wA[256][40];
  __shared__ unsigned short s_colT[64][40];

  int t = threadIdx.x;
  int pxt = blockIdx.x, b = blockIdx.y;
  int Po = Ho * Wo;
  const unsigned short* xTb = xT + (size_t)b * Hi * Wi * CIN;

  for (int e = t; e < 576; e += 256) {
    int k = e / 64, px = e % 64;
    int p = pxt * 64 + px;
    int i = p / Wo, j = p % Wo;
    int pc = (i * omStep) * omW + j * omStep;
    const float* omb = om + (size_t)b * 27 * omP;
    float offy = omb[(size_t)(2 * k) * omP + pc];
    float offx = omb[(size_t)(2 * k + 1) * omP + pc];
    float m = omb[(size_t)(18 + k) * omP + pc];
    float py = (float)(i * stride) - 1.0f + (float)(k / 3) + offy;
    float pxf = (float)(j * stride) - 1.0f + (float)(k % 3) + offx;
    float y0f = floorf(py), x0f = floorf(pxf);
    float wy = py - y0f, wx = pxf - x0f;
    int y0 = (int)y0f, x0 = (int)x0f;
    int y1 = y0 + 1, x1 = x0 + 1;
    float vy0 = (y0 >= 0 && y0 < Hi) ? 1.f : 0.f;
    float vy1 = (y1 >= 0 && y1 < Hi) ? 1.f : 0.f;
    float vx0 = (x0 >= 0 && x0 < Wi) ? 1.f : 0.f;
    float vx1 = (x1 >= 0 && x1 < Wi) ? 1.f : 0.f;
    float4 cw;
    cw.x = (1.f - wy) * (1.f - wx) * m * vy0 * vx0;
    cw.y = (1.f - wy) * wx * m * vy0 * vx1;
    cw.z = wy * (1.f - wx) * m * vy1 * vx0;
    cw.w = wy * wx * m * vy1 * vx1;
    s_cw[k][px] = cw;
    int y0c = min(max(y0, 0), Hi - 1), y1c = min(max(y1, 0), Hi - 1);
    int x0c = min(max(x0, 0), Wi - 1), x1c = min(max(x1, 0), Wi - 1);
    s_yy[k][px] = y0c | (y1c << 16);
    s_xx[k][px] = x0c | (x1c << 16);
  }

  floatx4 acc[4][4];
#pragma unroll
  for (int i = 0; i < 4; i++)
#pragma unroll
    for (int j = 0; j < 4; j++) acc[i][j] = (floatx4){0.f, 0.f, 0.f, 0.f};

  int lane = t & 63, wv = t >> 6;
  int quad = lane >> 4, ln = lane & 15;
  int wOc = wv * 64;

  for (int kc = 0; kc < 72; kc++) {
    int k = kc >> 3, cb = kc & 7;
    int kBase = k * 256 + cb * 32;
    __syncthreads();
#pragma unroll
    for (int e = 0; e < 4; e++) {
      int id = e * 256 + t;
      int oc = id >> 2, part = id & 3;
      *(short8*)&s_wA[oc][part * 8] =
          *(const short8*)(wtT + (size_t)oc * 2304 + kBase + part * 8);
    }
#pragma unroll
    for (int phs = 0; phs < 2; phs++) {
      int id = phs * 256 + t;
      int px = id >> 3, q = id & 7;
      int c4 = cb * 32 + q * 4;
      float4 cw = s_cw[k][px];
      int yy = s_yy[k][px], xx = s_xx[k][px];
      int y0 = yy & 0xffff, y1 = (yy >> 16) & 0xffff;
      int x0 = xx & 0xffff, x1 = (xx >> 16) & 0xffff;
      const unsigned short* base = xTb + c4;
      ushort4 v00 = *(const ushort4*)(base + (y0 * Wi + x0) * CIN);
      ushort4 v01 = *(const ushort4*)(base + (y0 * Wi + x1) * CIN);
      ushort4 v10 = *(const ushort4*)(base + (y1 * Wi + x0) * CIN);
      ushort4 v11 = *(const ushort4*)(base + (y1 * Wi + x1) * CIN);
      ushort4 r;
      r.x = f2b(cw.x * b2f(v00.x) + cw.y * b2f(v01.x) + cw.z * b2f(v10.x) +
                cw.w * b2f(v11.x));
      r.y = f2b(cw.x * b2f(v00.y) + cw.y * b2f(v01.y) + cw.z * b2f(v10.y) +
                cw.w * b2f(v11.y));
      r.z = f2b(cw.x * b2f(v00.z) + cw.y * b2f(v01.z) + cw.z * b2f(v10.z) +
                cw.w * b2f(v11.z));
      r.w = f2b(cw.x * b2f(v00.w) + cw.y * b2f(v01.w) + cw.z * b2f(v10.w) +
                cw.w * b2f(v11.w));
      *(ushort4*)&s_colT[px][q * 4] = r;
    }
    __syncthreads();
    short8 af[4], bfr[4];
#pragma unroll
    for (int i = 0; i < 4; i++)
      af[i] = *(const short8*)&s_wA[wOc + i * 16 + ln][quad * 8];
#pragma unroll
    for (int j = 0; j < 4; j++)
      bfr[j] = *(const short8*)&s_colT[j * 16 + ln][quad * 8];
#pragma unroll
    for (int i = 0; i < 4; i++)
#pragma unroll
      for (int j = 0; j < 4; j++)
        acc[i][j] = __builtin_amdgcn_mfma_f32_16x16x32_bf16(af[i], bfr[j],
                                                            acc[i][j], 0, 0, 0);
  }

#pragma unroll
  for (int i = 0; i < 4; i++) {
    int ocB = wOc + i * 16 + quad * 4;
#pragma unroll
    for (int j = 0; j < 4; j++) {
      int px = pxt * 64 + j * 16 + ln;
#pragma unroll
      for (int r = 0; r < 4; r++)
        outf[((size_t)b * COUT + ocB + r) * Po + px] = acc[i][j][r];
    }
  }
}

// ---------------------------------------------------------------------------
// Per-(b,c) sum / sum-of-squares. Grid (C, B), 256 thr.
// ---------------------------------------------------------------------------
__global__ __launch_bounds__(256) void chanstats_kernel(
    const float* __restrict__ f, int P, float* __restrict__ sum,
    float* __restrict__ sumsq) {
  int c = blockIdx.x, b = blockIdx.y;
  int tid = threadIdx.x;
  const float* fp = f + ((size_t)b * COUT + c) * P;
  float s = 0.0f, q = 0.0f;
  for (int i = tid; i < P; i += 256) {
    float v = fp[i];
    s += v;
    q += v * v;
  }
#pragma unroll
  for (int off = 32; off > 0; off >>= 1) {
    s += __shfl_down(s, off, 64);
    q += __shfl_down(q, off, 64);
  }
  __shared__ float rs[4], rq[4];
  int lane = tid & 63, wid = tid >> 6;
  if (lane == 0) { rs[wid] = s; rq[wid] = q; }
  __syncthreads();
  if (tid == 0) {
    sum[b * COUT + c] = rs[0] + rs[1] + rs[2] + rs[3];
    sumsq[b * COUT + c] = rq[0] + rq[1] + rq[2] + rq[3];
  }
}

// Same + resize-weighted sum (profile computed in-block). f spatial Wh x Wh.
__global__ __launch_bounds__(256) void chanstats3_kernel(
    const float* __restrict__ f, int Ph, int Wh, int Ho,
    float* __restrict__ sum, float* __restrict__ sumsq,
    float* __restrict__ wsum) {
  __shared__ float s_prof[64];
  int c = blockIdx.x, b = blockIdx.y;
  int tid = threadIdx.x;
  if (tid < Wh) s_prof[tid] = 0.f;
  __syncthreads();
  if (tid < Ho) {
    float r = (float)(Wh - 1) / (float)(Ho - 1);
    float sy = (float)tid * r;
    int yl = (int)floorf(sy);
    float fy = sy - (float)yl;
    int yh = min(yl + 1, Wh - 1);
    atomicAdd(&s_prof[yl], 1.f - fy);
    atomicAdd(&s_prof[yh], fy);
  }
  __syncthreads();
  const float* fp = f + ((size_t)b * COUT + c) * Ph;
  float s = 0.f, q = 0.f, w = 0.f;
  for (int p = tid; p < Ph; p += 256) {
    float v = fp[p];
    int i = p / Wh, j = p % Wh;
    s += v;
    q += v * v;
    w += v * s_prof[i] * s_prof[j];
  }
#pragma unroll
  for (int off = 32; off > 0; off >>= 1) {
    s += __shfl_down(s, off, 64);
    q += __shfl_down(q, off, 64);
    w += __shfl_down(w, off, 64);
  }
  __shared__ float rs[4], rq[4], rw[4];
  int lane = tid & 63, wid = tid >> 6;
  if (lane == 0) { rs[wid] = s; rq[wid] = q; rw[wid] = w; }
  __syncthreads();
  if (tid == 0) {
    sum[b * COUT + c] = rs[0] + rs[1] + rs[2] + rs[3];
    sumsq[b * COUT + c] = rq[0] + rq[1] + rq[2] + rq[3];
    wsum[b * COUT + c] = rw[0] + rw[1] + rw[2] + rw[3];
  }
}

// ---------------------------------------------------------------------------
// All per-level scalar prep: GN affines (<=3 paths), attention scalars,
// DyReLU coefficient MLP. One block, 256 threads.
// ---------------------------------------------------------------------------
__global__ __launch_bounds__(256) void prep_all_kernel(
    const float* __restrict__ sumM, const float* __restrict__ sqM,
    const float* __restrict__ sumL, const float* __restrict__ sqL,
    const float* __restrict__ sumH, const float* __restrict__ sqH,
    const float* __restrict__ swsum, const float* __restrict__ g_mid,
    const float* __restrict__ be_mid, const float* __restrict__ g_low,
    const float* __restrict__ be_low, const float* __restrict__ g_high,
    const float* __restrict__ be_high, const float* __restrict__ w_sa,
    const float* __restrict__ b_sa, const float* __restrict__ w1,
    const float* __restrict__ b1, const float* __restrict__ w2,
    const float* __restrict__ b2, float invP, float invPh, int hasLow,
    int hasHigh, float invn, float* __restrict__ Am, float* __restrict__ Bm,
    float* __restrict__ Al, float* __restrict__ Bl, float* __restrict__ Ah,
    float* __restrict__ Bh, float* __restrict__ svec,
    float* __restrict__ coef) {
  __shared__ float s_m[3][NB][GN_GROUPS], s_iv[3][NB][GN_GROUPS];
  __shared__ float s_mean[3][NB][COUT];
  __shared__ float s_s[3][NB];
  __shared__ float s_nm[NB][COUT];
  __shared__ float s_h[NB][64];
  int tid = threadIdx.x;

  if (tid < 96) {
    int path = tid / 32, b = (tid >> 4) & 1, g = tid & 15;
    int active = (path == 0) || (path == 1 && hasLow) || (path == 2 && hasHigh);
    if (active) {
      const float* su = path == 0 ? sumM : (path == 1 ? sumL : sumH);
      const float* sq = path == 0 ? sqM : (path == 1 ? sqL : sqH);
      float invN = ((path == 2) ? invPh : invP) * (1.f / 16.f);
      float s = 0.f, q = 0.f;
      for (int c = g * 16; c < g * 16 + 16; c++) {
        s += su[b * COUT + c];
        q += sq[b * COUT + c];
      }
      float m = s * invN;
      float v = q * invN - m * m;
      s_m[path][b][g] = m;
      s_iv[path][b][g] = rsqrtf(v + 1e-5f);
    }
  }
  __syncthreads();
  for (int idx = tid; idx < 3 * NB * COUT; idx += 256) {
    int path = idx / (NB * COUT);
    int r = idx % (NB * COUT);
    int b = r / COUT, c = r % COUT, g = c >> 4;
    int active = (path == 0) || (path == 1 && hasLow) || (path == 2 && hasHigh);
    if (active) {
      const float* ga = path == 0 ? g_mid : (path == 1 ? g_low : g_high);
      const float* be = path == 0 ? be_mid : (path == 1 ? be_low : be_high);
      float a = ga[c] * s_iv[path][b][g];
      float bb = be[c] - s_m[path][b][g] * a;
      float mean;
      if (path == 2)
        mean = a * (swsum[r] * invP) + bb;
      else {
        const float* su = path == 0 ? sumM : sumL;
        mean = a * (su[r] * invP) + bb;
      }
      float* Ad = path == 0 ? Am : (path == 1 ? Al : Ah);
      float* Bd = path == 0 ? Bm : (path == 1 ? Bl : Bh);
      Ad[r] = a;
      Bd[r] = bb;
      s_mean[path][b][c] = mean;
    }
  }
  __syncthreads();
  if (tid < 6) {
    int path = tid >> 1, b = tid & 1;
    int active = (path == 0) || (path == 1 && hasLow) || (path == 2 && hasHigh);
    float s = 0.f;
    if (active) {
      float t = 0.f;
      for (int c = 0; c < COUT; c++) t += s_mean[path][b][c] * w_sa[c];
      t += b_sa[0];
      t = fmaxf(t, 0.f);
      s = fminf(fmaxf(t + 3.f, 0.f), 6.f) * (1.f / 6.f);
      svec[path * NB + b] = s;
    }
    s_s[path][b] = s;
  }
  __syncthreads();
  for (int idx = tid; idx < NB * COUT; idx += 256) {
    int b = idx / COUT, c = idx % COUT;
    float v = s_s[0][b] * s_mean[0][b][c];
    if (hasLow) v += s_s[1][b] * s_mean[1][b][c];
    if (hasHigh) v += s_s[2][b] * s_mean[2][b][c];
    s_nm[b][c] = v * invn;
  }
  __syncthreads();
  if (tid < NB * 64) {
    int b = tid / 64, j = tid % 64;
    float t = b1[j];
    for (int c = 0; c < COUT; c++) t += s_nm[b][c] * w1[j * COUT + c];
    s_h[b][j] = fmaxf(t, 0.f);
  }
  __syncthreads();
  for (int idx = tid; idx < NB * 1024; idx += 256) {
    int b = idx / 1024, i = idx % 1024;
    float t = b2[i];
    for (int j = 0; j < 64; j++) t += s_h[b][j] * w2[i * 64 + j];
    coef[idx] = fminf(fmaxf(t + 3.f, 0.f), 6.f) * (1.f / 6.f) - 0.5f;
  }
}

// ---------------------------------------------------------------------------
// Fused epilogue: GN-affine+scale of mid (+low) (+bilinear-resized high),
// then DyReLU. One pass over the output.
// ---------------------------------------------------------------------------
__global__ __launch_bounds__(256) void fused_apply_kernel(
    const float* __restrict__ featM, const float* __restrict__ featL,
    const float* __restrict__ featH, const float* __restrict__ Am,
    const float* __restrict__ Bm, const float* __restrict__ Al,
    const float* __restrict__ Bl, const float* __restrict__ Ah,
    const float* __restrict__ Bh, const float* __restrict__ svec,
    const float* __restrict__ coef, float* __restrict__ out, int P, int Ho,
    int Hh, int hasLow, int hasHigh, float invn) {
  int idx = blockIdx.x * 256 + threadIdx.x;
  int bc = idx / P, p = idx % P;
  int b = bc / COUT, c = bc % COUT;
  float v = (featM[idx] * Am[bc] + Bm[bc]) * svec[b];
  if (hasLow) v += (featL[idx] * Al[bc] + Bl[bc]) * svec[2 + b];
  if (hasHigh) {
    int Y = p / Ho, X = p % Ho;
    float r = (float)(Hh - 1) / (float)(Ho - 1);
    float sy = (float)Y * r, sx = (float)X * r;
    int yl = (int)floorf(sy), xl = (int)floorf(sx);
    int yh = min(yl + 1, Hh - 1), xh = min(xl + 1, Hh - 1);
    float wy = sy - (float)yl, wx = sx - (float)xl;
    const float* fp = featH + (size_t)bc * Hh * Hh;
    float t0 = fp[yl * Hh + xl] * (1.f - wx) + fp[yl * Hh + xh] * wx;
    float t1 = fp[yh * Hh + xl] * (1.f - wx) + fp[yh * Hh + xh] * wx;
    v += ((t0 * (1.f - wy) + t1 * wy) * Ah[bc] + Bh[bc]) * svec[4 + b];
  }
  float x = v * invn;
  float a1 = coef[b * 1024 + c] * 2.f + 1.f;
  float b1v = coef[b * 1024 + 256 + c];
  float a2 = coef[b * 1024 + 512 + c] * 2.f;
  float b2v = coef[b * 1024 + 768 + c];
  out[idx] = fmaxf(x * a1 + b1v, x * a2 + b2v);
}

// ---------------------------------------------------------------------------
extern "C" void kernel_launch(void* const* d_in, const int* in_sizes, int n_in,
                              void* d_out, int out_size, void* d_ws,
                              size_t ws_size, hipStream_t stream) {
  (void)in_sizes; (void)n_in; (void)out_size; (void)ws_size;
  const float* x[3] = {(const float*)d_in[0], (const float*)d_in[1],
                       (const float*)d_in[2]};
  const float* w_off = (const float*)d_in[3];
  const float* b_off = (const float*)d_in[4];
  const float* w_mid = (const float*)d_in[5];
  const float* g_mid = (const float*)d_in[6];
  const float* be_mid = (const float*)d_in[7];
  const float* w_low = (const float*)d_in[8];
  const float* g_low = (const float*)d_in[9];
  const float* be_low = (const float*)d_in[10];
  const float* w_high = (const float*)d_in[11];
  const float* g_high = (const float*)d_in[12];
  const float* be_high = (const float*)d_in[13];
  const float* w_sa = (const float*)d_in[14];
  const float* b_sa = (const float*)d_in[15];
  const float* w_dy1 = (const float*)d_in[16];
  const float* b_dy1 = (const float*)d_in[17];
  const float* w_dy2 = (const float*)d_in[18];
  const float* b_dy2 = (const float*)d_in[19];

  float* out = (float*)d_out;
  char* wsb = (char*)d_ws;
  size_t o = 0;
  unsigned short* xT0 = (unsigned short*)(wsb + o); o += 16777216;
  unsigned short* xT1 = (unsigned short*)(wsb + o); o += 4194304;
  unsigned short* xT2 = (unsigned short*)(wsb + o); o += 1048576;
  unsigned short* wtm = (unsigned short*)(wsb + o); o += 1179648;
  unsigned short* wtl = (unsigned short*)(wsb + o); o += 1179648;
  unsigned short* wth = (unsigned short*)(wsb + o); o += 1179648;
  unsigned short* wo  = (unsigned short*)(wsb + o); o += 294912;
  float* om = (float*)(wsb + o); o += 3538944;
  float* arena = (float*)(wsb + o); o += 41943040;  // feat arena (+xLo alias)
  float* sumM = (float*)(wsb + o); o += 2048;
  float* sqM = (float*)(wsb + o); o += 2048;
  float* sumL = (float*)(wsb + o); o += 2048;
  float* sqL = (float*)(wsb + o); o += 2048;
  float* sumH = (float*)(wsb + o); o += 2048;
  float* sqH = (float*)(wsb + o); o += 2048;
  float* Swsum = (float*)(wsb + o); o += 2048;
  float* Am = (float*)(wsb + o); o += 2048;
  float* Bm = (float*)(wsb + o); o += 2048;
  float* Al = (float*)(wsb + o); o += 2048;
  float* Bl = (float*)(wsb + o); o += 2048;
  float* Ah = (float*)(wsb + o); o += 2048;
  float* Bh = (float*)(wsb + o); o += 2048;
  float* svec = (float*)(wsb + o); o += 64;
  float* dycoef = (float*)(wsb + o); o += 8192;

  const unsigned short* xT[3] = {xT0, xT1, xT2};
  unsigned short* xLo = (unsigned short*)arena;

  transpose_kernel<<<dim3(256, 4, NB), 256, 0, stream>>>(x[0], xT0, 16384);
  transpose_kernel<<<dim3(64, 4, NB), 256, 0, stream>>>(x[1], xT1, 4096);
  transpose_kernel<<<dim3(16, 4, NB), 256, 0, stream>>>(x[2], xT2, 1024);
  repack_w_kernel<<<2304, 256, 0, stream>>>(w_mid, wtm);
  repack_w_kernel<<<2304, 256, 0, stream>>>(w_low, wtl);
  repack_w_kernel<<<2304, 256, 0, stream>>>(w_high, wth);
  repack_wo_kernel<<<576, 256, 0, stream>>>(w_off, wo);

  const int Hs[3] = {128, 64, 32};
  const int lws[3] = {7, 6, 5};
  const size_t outOff[3] = {0, 8388608, 10485760};
  const int nterm[3] = {2, 3, 2};

  for (int l = 0; l < 3; l++) {
    int H = Hs[l];
    int P = H * H;
    int hasLow = (l > 0), hasHigh = (l < 2);
    int Hh = H / 2, Ph = Hh * Hh;
    float* outl = out + outOff[l];
    float* featM = arena;
    float* featL = arena + (size_t)512 * P;
    float* featH = arena + (size_t)(hasLow ? 1024 : 512) * P;

    // x_lo for this level (scratch aliasing the feat arena; consumed by
    // conv_offset before any mdconv writes feat).
    transpose_lo_kernel<<<dim3(P / 64, 4, NB), 256, 0, stream>>>(x[l], xLo, P);
    conv_offset_mfma_kernel<<<dim3(P / 64, NB), 256, 0, stream>>>(
        xT[l], xLo, wo, b_off, om, H, H, lws[l]);

    mdconv_kernel<<<dim3(P / 64, NB), 256, 0, stream>>>(
        xT[l], H, H, om, H, P, 1, wtm, featM, H, H, 1);
    chanstats_kernel<<<dim3(COUT, NB), 256, 0, stream>>>(featM, P, sumM, sqM);

    if (hasLow) {
      int Hp = Hs[l - 1];
      mdconv_kernel<<<dim3(P / 64, NB), 256, 0, stream>>>(
          xT[l - 1], Hp, Hp, om, H, P, 1, wtl, featL, H, H, 2);
      chanstats_kernel<<<dim3(COUT, NB), 256, 0, stream>>>(featL, P, sumL, sqL);
    }
    if (hasHigh) {
      mdconv_kernel<<<dim3(Ph / 64, NB), 256, 0, stream>>>(
          xT[l + 1], Hh, Hh, om, H, P, 2, wth, featH, Hh, Hh, 1);
      chanstats3_kernel<<<dim3(COUT, NB), 256, 0, stream>>>(
          featH, Ph, Hh, H, sumH, sqH, Swsum);
    }

    prep_all_kernel<<<1, 256, 0, stream>>>(
        sumM, sqM, sumL, sqL, sumH, sqH, Swsum, g_mid, be_mid, g_low, be_low,
        g_high, be_high, w_sa, b_sa, w_dy1, b_dy1, w_dy2, b_dy2, 1.0f / P,
        1.0f / Ph, hasLow, hasHigh, 1.0f / nterm[l], Am, Bm, Al, Bl, Ah, Bh,
        svec, dycoef);

    fused_apply_kernel<<<(NB * COUT * P) / 256, 256, 0, stream>>>(
        featM, featL, featH, Am, Bm, Al, Bl, Ah, Bh, svec, dycoef, outl, P, H,
        Hh, hasLow, hasHigh, 1.0f / nterm[l]);
  }
}

// Round 4
// 698.983 us; speedup vs baseline: 14.2601x; 2.0274x over previous
//
#include <hip/hip_runtime.h>
#include <hip/hip_bf16.h>
#include <math.h>

#define CIN 256
#define COUT 256
#define NB 2
#define GN_GROUPS 16

typedef __attribute__((ext_vector_type(8))) short short8;
typedef __attribute__((ext_vector_type(4))) float floatx4;

__device__ __forceinline__ float b2f(unsigned short u) {
  union { unsigned int i; float f; } v;
  v.i = ((unsigned int)u) << 16;
  return v.f;
}
__device__ __forceinline__ unsigned short f2b(float f) {
  union { float f; unsigned int i; } v;
  v.f = f;
  unsigned int r = (v.i + 0x7FFFu + ((v.i >> 16) & 1u)) >> 16;
  return (unsigned short)r;
}
__device__ __forceinline__ float lo2f(unsigned int u) {
  union { unsigned int i; float f; } v;
  v.i = u << 16;
  return v.f;
}
__device__ __forceinline__ float hi2f(unsigned int u) {
  union { unsigned int i; float f; } v;
  v.i = u & 0xffff0000u;
  return v.f;
}
__device__ __forceinline__ unsigned int pk2(float a, float b) {
  union { __hip_bfloat162 h; unsigned int u; } v;
  v.h = __float22bfloat162_rn(float2{a, b});
  return v.u;
}

// ---------------------------------------------------------------------------
// NCHW fp32 -> NHWC bf16 hi + residual lo, one pass. grid (P/64, 4, B).
// ---------------------------------------------------------------------------
__global__ __launch_bounds__(256) void transpose_kernel(
    const float* __restrict__ x, unsigned short* __restrict__ xT,
    unsigned short* __restrict__ xLo, int P) {
  __shared__ float tile[64][65];
  int pBase = blockIdx.x * 64, cBase = blockIdx.y * 64, b = blockIdx.z;
  int t = threadIdx.x;
  int pl = t & 63, ch = t >> 6;
  const float* xb = x + ((size_t)b * CIN + cBase) * P + pBase;
#pragma unroll
  for (int e = 0; e < 16; e++) {
    int c = ch * 16 + e;
    tile[c][pl] = xb[(size_t)c * P + pl];
  }
  __syncthreads();
  size_t obase = ((size_t)b * P + pBase) * CIN + cBase;
  int cl = t & 63, pr = t >> 6;
#pragma unroll
  for (int e = 0; e < 16; e++) {
    int p = pr * 16 + e;
    float v = tile[cl][p];
    unsigned short h = f2b(v);
    xT[obase + (size_t)p * CIN + cl] = h;
    xLo[obase + (size_t)p * CIN + cl] = f2b(v - b2f(h));
  }
}

// ---------------------------------------------------------------------------
// Repack mdconv weight (256,256,3,3) fp32 -> bf16 [oc][K], K = tap*256 + c
// ---------------------------------------------------------------------------
__global__ void repack_w_kernel(const float* __restrict__ w,
                                unsigned short* __restrict__ wt) {
  int idx = blockIdx.x * 256 + threadIdx.x;  // 589824
  int oc = idx / 2304, kk = idx % 2304;
  int k = kk >> 8, c = kk & 255;
  wt[idx] = f2b(w[(size_t)oc * 2304 + c * 9 + k]);
}

// Offset-conv weight (27,256,3,3) -> bf16 wo[sel][tap][cb][oc32][ch32]
__global__ void repack_wo_kernel(const float* __restrict__ w,
                                 unsigned short* __restrict__ wo) {
  int idx = blockIdx.x * 256 + threadIdx.x;  // 2*73728
  int sel = idx / 73728;
  int r = idx % 73728;
  int k = r / 8192;
  int r2 = r % 8192;
  int cbk = r2 / 1024;
  int oc = (r2 / 32) % 32;
  int ch = r2 % 32;
  int c = cbk * 32 + ch;
  float val = (oc < 27) ? w[(size_t)oc * 2304 + c * 9 + k] : 0.0f;
  float hi = b2f(f2b(val));
  wo[idx] = sel ? f2b(val - hi) : f2b(val);
}

// ---------------------------------------------------------------------------
// Offset conv v2: halo-staged LDS + MFMA, split-bf16, batched over levels.
// Block: 256 thr (4 waves); strip of 64 px; per cb: stage hi+lo halo tile,
// then 9 taps x 6 MFMA per wave (whi*bhi, wlo*bhi, whi*blo for 2 oc-tiles).
// ---------------------------------------------------------------------------
struct CoL {
  const unsigned short* xhi;
  const unsigned short* xlo;
  float* om;
  int H, W, Cs, cshift, Rs, P;
};
struct CoB { CoL L[3]; int off[4]; };

__global__ __launch_bounds__(256) void conv_offset_kernel(
    CoB B, const unsigned short* __restrict__ wo,
    const float* __restrict__ bias) {
  __shared__ unsigned short s_hi[204 * 40];
  __shared__ unsigned short s_lo[204 * 40];
  int bx = blockIdx.x;
  int li = (bx >= B.off[1] ? 1 : 0) + (bx >= B.off[2] ? 1 : 0);
  CoL L = B.L[li];
  int local = bx - B.off[li];
  int tpb = L.P / 64;
  int b = local / tpb, pxt = local % tpb;
  int t = threadIdx.x;
  int pbase = pxt * 64;
  int r0 = pbase / L.W;
  int c0 = pbase % L.W;
  int Ct = L.Cs + 2;
  int Npos = Ct * (L.Rs + 2);
  const unsigned short* xhib = L.xhi + (size_t)b * L.P * CIN;
  const unsigned short* xlob = L.xlo + (size_t)b * L.P * CIN;

  int lane = t & 63, wv = t >> 6, quad = lane >> 4, ln = lane & 15;
  int pl = wv * 16 + ln;
  int pi_ = pl >> L.cshift;
  int pj_ = pl & (L.Cs - 1);

  floatx4 acc0 = {0.f, 0.f, 0.f, 0.f}, acc1 = {0.f, 0.f, 0.f, 0.f};

  for (int cb = 0; cb < 8; cb++) {
    __syncthreads();
    for (int e = t; e < Npos * 4; e += 256) {
      int pos = e >> 2, oct = e & 3;
      int r = pos / Ct, c = pos % Ct;
      int gy = r0 - 1 + r, gx = c0 - 1 + c;
      uint4 vhi = {0, 0, 0, 0}, vlo = {0, 0, 0, 0};
      if (gy >= 0 && gy < L.H && gx >= 0 && gx < L.W) {
        size_t off = ((size_t)(gy * L.W + gx)) * CIN + cb * 32 + oct * 8;
        vhi = *(const uint4*)(xhib + off);
        vlo = *(const uint4*)(xlob + off);
      }
      *(uint4*)&s_hi[pos * 40 + oct * 8] = vhi;
      *(uint4*)&s_lo[pos * 40 + oct * 8] = vlo;
    }
    __syncthreads();
#pragma unroll
    for (int tap = 0; tap < 9; tap++) {
      int dy = tap / 3 - 1, dx = tap % 3 - 1;
      const unsigned short* wb0 = wo + (size_t)((0 * 9 + tap) * 8 + cb) * 1024;
      const unsigned short* wb1 = wo + (size_t)((1 * 9 + tap) * 8 + cb) * 1024;
      short8 whi0 = *(const short8*)(wb0 + ln * 32 + quad * 8);
      short8 whi1 = *(const short8*)(wb0 + (16 + ln) * 32 + quad * 8);
      short8 wlo0 = *(const short8*)(wb1 + ln * 32 + quad * 8);
      short8 wlo1 = *(const short8*)(wb1 + (16 + ln) * 32 + quad * 8);
      int pos = (pi_ + dy + 1) * Ct + (pj_ + dx + 1);
      short8 bhi = *(const short8*)&s_hi[pos * 40 + quad * 8];
      short8 blo = *(const short8*)&s_lo[pos * 40 + quad * 8];
      acc0 = __builtin_amdgcn_mfma_f32_16x16x32_bf16(whi0, bhi, acc0, 0, 0, 0);
      acc1 = __builtin_amdgcn_mfma_f32_16x16x32_bf16(whi1, bhi, acc1, 0, 0, 0);
      acc0 = __builtin_amdgcn_mfma_f32_16x16x32_bf16(wlo0, bhi, acc0, 0, 0, 0);
      acc1 = __builtin_amdgcn_mfma_f32_16x16x32_bf16(wlo1, bhi, acc1, 0, 0, 0);
      acc0 = __builtin_amdgcn_mfma_f32_16x16x32_bf16(whi0, blo, acc0, 0, 0, 0);
      acc1 = __builtin_amdgcn_mfma_f32_16x16x32_bf16(whi1, blo, acc1, 0, 0, 0);
    }
  }

  int px = pbase + pl;
#pragma unroll
  for (int i2 = 0; i2 < 2; i2++) {
#pragma unroll
    for (int r = 0; r < 4; r++) {
      int oc = i2 * 16 + quad * 4 + r;
      if (oc < 27) {
        float val = (i2 == 0 ? acc0[r] : acc1[r]) + bias[oc];
        if (oc >= 18) val = 1.f / (1.f + __expf(-val));
        L.om[((size_t)b * 27 + oc) * L.P + px] = val;
      }
    }
  }
}

// ---------------------------------------------------------------------------
// Modulated deformable conv v3: bf16 MFMA implicit GEMM, double-buffered LDS,
// one barrier per K-chunk, gather loads for chunk k+1 issued before MFMAs of
// chunk k. Batched over the level's paths (mid/low/high).
// ---------------------------------------------------------------------------
struct MdP {
  const unsigned short* xT;
  const unsigned short* wt;
  float* outf;
  int Hi, Wi, Ho, Wo, stride, omStep, ntile;
};
struct MdBatch { MdP p[3]; const float* om; int omW, omP; int off[4]; };

__global__ __launch_bounds__(256, 2) void mdconv_kernel(MdBatch B) {
  __shared__ float4 s_cw[9][64];
  __shared__ int s_yy[9][64];
  __shared__ int s_xx[9][64];
  __shared__ unsigned short s_w[2][256][40];
  __shared__ unsigned short s_col[2][64][40];

  int bx = blockIdx.x;
  int pidx = (bx >= B.off[1] ? 1 : 0) + (bx >= B.off[2] ? 1 : 0);
  MdP P = B.p[pidx];
  int local = bx - B.off[pidx];
  int b = local / P.ntile, pxt = local % P.ntile;
  int Po = P.Ho * P.Wo;
  const unsigned short* xTb = P.xT + (size_t)b * P.Hi * P.Wi * CIN;

  int t = threadIdx.x;
  // Phase 0: sampling metadata for 9 taps x 64 px
  for (int e = t; e < 576; e += 256) {
    int k = e / 64, px = e % 64;
    int p = pxt * 64 + px;
    int i = p / P.Wo, j = p % P.Wo;
    int pc = (i * P.omStep) * B.omW + j * P.omStep;
    const float* omb = B.om + (size_t)b * 27 * B.omP;
    float offy = omb[(size_t)(2 * k) * B.omP + pc];
    float offx = omb[(size_t)(2 * k + 1) * B.omP + pc];
    float m = omb[(size_t)(18 + k) * B.omP + pc];
    float py = (float)(i * P.stride) - 1.0f + (float)(k / 3) + offy;
    float pxf = (float)(j * P.stride) - 1.0f + (float)(k % 3) + offx;
    float y0f = floorf(py), x0f = floorf(pxf);
    float wy = py - y0f, wx = pxf - x0f;
    int y0 = (int)y0f, x0 = (int)x0f;
    int y1 = y0 + 1, x1 = x0 + 1;
    float vy0 = (y0 >= 0 && y0 < P.Hi) ? 1.f : 0.f;
    float vy1 = (y1 >= 0 && y1 < P.Hi) ? 1.f : 0.f;
    float vx0 = (x0 >= 0 && x0 < P.Wi) ? 1.f : 0.f;
    float vx1 = (x1 >= 0 && x1 < P.Wi) ? 1.f : 0.f;
    float4 cw;
    cw.x = (1.f - wy) * (1.f - wx) * m * vy0 * vx0;
    cw.y = (1.f - wy) * wx * m * vy0 * vx1;
    cw.z = wy * (1.f - wx) * m * vy1 * vx0;
    cw.w = wy * wx * m * vy1 * vx1;
    s_cw[k][px] = cw;
    int y0c = min(max(y0, 0), P.Hi - 1), y1c = min(max(y1, 0), P.Hi - 1);
    int x0c = min(max(x0, 0), P.Wi - 1), x1c = min(max(x1, 0), P.Wi - 1);
    s_yy[k][px] = y0c | (y1c << 16);
    s_xx[k][px] = x0c | (x1c << 16);
  }
  __syncthreads();

  floatx4 acc[4][4];
#pragma unroll
  for (int i = 0; i < 4; i++)
#pragma unroll
    for (int j = 0; j < 4; j++) acc[i][j] = (floatx4){0.f, 0.f, 0.f, 0.f};

  int lane = t & 63, wv = t >> 6;
  int quad = lane >> 4, ln = lane & 15;
  int wOc = wv * 64;
  int gpx = t >> 2, goct = t & 3;  // gather item: (px, 8-ch octet)

  short8 wreg[4];
  uint4 greg[4];

  // prologue: load + stage chunk 0 into buf 0
  {
    int kBase = 0;
#pragma unroll
    for (int e = 0; e < 4; e++) {
      int id = e * 256 + t;
      int oc = id >> 2, part = id & 3;
      wreg[e] = *(const short8*)(P.wt + (size_t)oc * 2304 + kBase + part * 8);
    }
    int yy = s_yy[0][gpx], xx = s_xx[0][gpx];
    int y0 = yy & 0xffff, y1 = (yy >> 16) & 0xffff;
    int x0 = xx & 0xffff, x1 = (xx >> 16) & 0xffff;
    const unsigned short* base = xTb + goct * 8;
    greg[0] = *(const uint4*)(base + (size_t)(y0 * P.Wi + x0) * CIN);
    greg[1] = *(const uint4*)(base + (size_t)(y0 * P.Wi + x1) * CIN);
    greg[2] = *(const uint4*)(base + (size_t)(y1 * P.Wi + x0) * CIN);
    greg[3] = *(const uint4*)(base + (size_t)(y1 * P.Wi + x1) * CIN);
#pragma unroll
    for (int e = 0; e < 4; e++) {
      int id = e * 256 + t;
      int oc = id >> 2, part = id & 3;
      *(short8*)&s_w[0][oc][part * 8] = wreg[e];
    }
    float4 cw = s_cw[0][gpx];
    float r[8];
#pragma unroll
    for (int j = 0; j < 4; j++) {
      unsigned int a = ((unsigned int*)&greg[0])[j];
      unsigned int bb = ((unsigned int*)&greg[1])[j];
      unsigned int c = ((unsigned int*)&greg[2])[j];
      unsigned int d = ((unsigned int*)&greg[3])[j];
      r[2 * j] = cw.x * lo2f(a) + cw.y * lo2f(bb) + cw.z * lo2f(c) + cw.w * lo2f(d);
      r[2 * j + 1] = cw.x * hi2f(a) + cw.y * hi2f(bb) + cw.z * hi2f(c) + cw.w * hi2f(d);
    }
    uint4 packed;
    packed.x = pk2(r[0], r[1]);
    packed.y = pk2(r[2], r[3]);
    packed.z = pk2(r[4], r[5]);
    packed.w = pk2(r[6], r[7]);
    *(uint4*)&s_col[0][gpx][goct * 8] = packed;
  }
  __syncthreads();

  for (int kc = 0; kc < 72; kc++) {
    int cur = kc & 1, nxt = cur ^ 1;
    int kn = kc + 1;
    if (kn < 72) {
      int k = kn >> 3, cbk = kn & 7;
      int kBase = k * 256 + cbk * 32;
#pragma unroll
      for (int e = 0; e < 4; e++) {
        int id = e * 256 + t;
        int oc = id >> 2, part = id & 3;
        wreg[e] = *(const short8*)(P.wt + (size_t)oc * 2304 + kBase + part * 8);
      }
      int yy = s_yy[k][gpx], xx = s_xx[k][gpx];
      int y0 = yy & 0xffff, y1 = (yy >> 16) & 0xffff;
      int x0 = xx & 0xffff, x1 = (xx >> 16) & 0xffff;
      const unsigned short* base = xTb + cbk * 32 + goct * 8;
      greg[0] = *(const uint4*)(base + (size_t)(y0 * P.Wi + x0) * CIN);
      greg[1] = *(const uint4*)(base + (size_t)(y0 * P.Wi + x1) * CIN);
      greg[2] = *(const uint4*)(base + (size_t)(y1 * P.Wi + x0) * CIN);
      greg[3] = *(const uint4*)(base + (size_t)(y1 * P.Wi + x1) * CIN);
    }
    // MFMA on current buffers
    short8 af[4], bfr[4];
#pragma unroll
    for (int i = 0; i < 4; i++)
      af[i] = *(const short8*)&s_w[cur][wOc + i * 16 + ln][quad * 8];
#pragma unroll
    for (int j = 0; j < 4; j++)
      bfr[j] = *(const short8*)&s_col[cur][j * 16 + ln][quad * 8];
#pragma unroll
    for (int i = 0; i < 4; i++)
#pragma unroll
      for (int j = 0; j < 4; j++)
        acc[i][j] = __builtin_amdgcn_mfma_f32_16x16x32_bf16(af[i], bfr[j],
                                                            acc[i][j], 0, 0, 0);
    if (kn < 72) {
#pragma unroll
      for (int e = 0; e < 4; e++) {
        int id = e * 256 + t;
        int oc = id >> 2, part = id & 3;
        *(short8*)&s_w[nxt][oc][part * 8] = wreg[e];
      }
      float4 cw = s_cw[kn >> 3][gpx];
      float r[8];
#pragma unroll
      for (int j = 0; j < 4; j++) {
        unsigned int a = ((unsigned int*)&greg[0])[j];
        unsigned int bb = ((unsigned int*)&greg[1])[j];
        unsigned int c = ((unsigned int*)&greg[2])[j];
        unsigned int d = ((unsigned int*)&greg[3])[j];
        r[2 * j] = cw.x * lo2f(a) + cw.y * lo2f(bb) + cw.z * lo2f(c) + cw.w * lo2f(d);
        r[2 * j + 1] = cw.x * hi2f(a) + cw.y * hi2f(bb) + cw.z * hi2f(c) + cw.w * hi2f(d);
      }
      uint4 packed;
      packed.x = pk2(r[0], r[1]);
      packed.y = pk2(r[2], r[3]);
      packed.z = pk2(r[4], r[5]);
      packed.w = pk2(r[6], r[7]);
      *(uint4*)&s_col[nxt][gpx][goct * 8] = packed;
    }
    __syncthreads();
  }

  // epilogue: C/D layout col=lane&15 (px), row=(lane>>4)*4+reg (oc)
#pragma unroll
  for (int i = 0; i < 4; i++) {
    int ocB = wOc + i * 16 + quad * 4;
#pragma unroll
    for (int j = 0; j < 4; j++) {
      int px = pxt * 64 + j * 16 + ln;
#pragma unroll
      for (int r = 0; r < 4; r++)
        P.outf[((size_t)b * COUT + ocB + r) * Po + px] = acc[i][j][r];
    }
  }
}

// ---------------------------------------------------------------------------
// Per-(b,c) sum / sum-of-squares. Grid (C, B), 256 thr.
// ---------------------------------------------------------------------------
__global__ __launch_bounds__(256) void chanstats_kernel(
    const float* __restrict__ f, int P, float* __restrict__ sum,
    float* __restrict__ sumsq) {
  int c = blockIdx.x, b = blockIdx.y;
  int tid = threadIdx.x;
  const float* fp = f + ((size_t)b * COUT + c) * P;
  float s = 0.0f, q = 0.0f;
  for (int i = tid; i < P; i += 256) {
    float v = fp[i];
    s += v;
    q += v * v;
  }
#pragma unroll
  for (int off = 32; off > 0; off >>= 1) {
    s += __shfl_down(s, off, 64);
    q += __shfl_down(q, off, 64);
  }
  __shared__ float rs[4], rq[4];
  int lane = tid & 63, wid = tid >> 6;
  if (lane == 0) { rs[wid] = s; rq[wid] = q; }
  __syncthreads();
  if (tid == 0) {
    sum[b * COUT + c] = rs[0] + rs[1] + rs[2] + rs[3];
    sumsq[b * COUT + c] = rq[0] + rq[1] + rq[2] + rq[3];
  }
}

// Same + resize-weighted sum (profile computed in-block). f spatial Wh x Wh.
__global__ __launch_bounds__(256) void chanstats3_kernel(
    const float* __restrict__ f, int Ph, int Wh, int Ho,
    float* __restrict__ sum, float* __restrict__ sumsq,
    float* __restrict__ wsum) {
  __shared__ float s_prof[64];
  int c = blockIdx.x, b = blockIdx.y;
  int tid = threadIdx.x;
  if (tid < Wh) s_prof[tid] = 0.f;
  __syncthreads();
  if (tid < Ho) {
    float r = (float)(Wh - 1) / (float)(Ho - 1);
    float sy = (float)tid * r;
    int yl = (int)floorf(sy);
    float fy = sy - (float)yl;
    int yh = min(yl + 1, Wh - 1);
    atomicAdd(&s_prof[yl], 1.f - fy);
    atomicAdd(&s_prof[yh], fy);
  }
  __syncthreads();
  const float* fp = f + ((size_t)b * COUT + c) * Ph;
  float s = 0.f, q = 0.f, w = 0.f;
  for (int p = tid; p < Ph; p += 256) {
    float v = fp[p];
    int i = p / Wh, j = p % Wh;
    s += v;
    q += v * v;
    w += v * s_prof[i] * s_prof[j];
  }
#pragma unroll
  for (int off = 32; off > 0; off >>= 1) {
    s += __shfl_down(s, off, 64);
    q += __shfl_down(q, off, 64);
    w += __shfl_down(w, off, 64);
  }
  __shared__ float rs[4], rq[4], rw[4];
  int lane = tid & 63, wid = tid >> 6;
  if (lane == 0) { rs[wid] = s; rq[wid] = q; rw[wid] = w; }
  __syncthreads();
  if (tid == 0) {
    sum[b * COUT + c] = rs[0] + rs[1] + rs[2] + rs[3];
    sumsq[b * COUT + c] = rq[0] + rq[1] + rq[2] + rq[3];
    wsum[b * COUT + c] = rw[0] + rw[1] + rw[2] + rw[3];
  }
}

// ---------------------------------------------------------------------------
// All per-level scalar prep (GN affines, attention scalars, DyReLU MLP).
// ---------------------------------------------------------------------------
__global__ __launch_bounds__(256) void prep_all_kernel(
    const float* __restrict__ sumM, const float* __restrict__ sqM,
    const float* __restrict__ sumL, const float* __restrict__ sqL,
    const float* __restrict__ sumH, const float* __restrict__ sqH,
    const float* __restrict__ swsum, const float* __restrict__ g_mid,
    const float* __restrict__ be_mid, const float* __restrict__ g_low,
    const float* __restrict__ be_low, const float* __restrict__ g_high,
    const float* __restrict__ be_high, const float* __restrict__ w_sa,
    const float* __restrict__ b_sa, const float* __restrict__ w1,
    const float* __restrict__ b1, const float* __restrict__ w2,
    const float* __restrict__ b2, float invP, float invPh, int hasLow,
    int hasHigh, float invn, float* __restrict__ Am, float* __restrict__ Bm,
    float* __restrict__ Al, float* __restrict__ Bl, float* __restrict__ Ah,
    float* __restrict__ Bh, float* __restrict__ svec,
    float* __restrict__ coef) {
  __shared__ float s_m[3][NB][GN_GROUPS], s_iv[3][NB][GN_GROUPS];
  __shared__ float s_mean[3][NB][COUT];
  __shared__ float s_s[3][NB];
  __shared__ float s_nm[NB][COUT];
  __shared__ float s_h[NB][64];
  int tid = threadIdx.x;

  if (tid < 96) {
    int path = tid / 32, b = (tid >> 4) & 1, g = tid & 15;
    int active = (path == 0) || (path == 1 && hasLow) || (path == 2 && hasHigh);
    if (active) {
      const float* su = path == 0 ? sumM : (path == 1 ? sumL : sumH);
      const float* sq = path == 0 ? sqM : (path == 1 ? sqL : sqH);
      float invN = ((path == 2) ? invPh : invP) * (1.f / 16.f);
      float s = 0.f, q = 0.f;
      for (int c = g * 16; c < g * 16 + 16; c++) {
        s += su[b * COUT + c];
        q += sq[b * COUT + c];
      }
      float m = s * invN;
      float v = q * invN - m * m;
      s_m[path][b][g] = m;
      s_iv[path][b][g] = rsqrtf(v + 1e-5f);
    }
  }
  __syncthreads();
  for (int idx = tid; idx < 3 * NB * COUT; idx += 256) {
    int path = idx / (NB * COUT);
    int r = idx % (NB * COUT);
    int b = r / COUT, c = r % COUT, g = c >> 4;
    int active = (path == 0) || (path == 1 && hasLow) || (path == 2 && hasHigh);
    if (active) {
      const float* ga = path == 0 ? g_mid : (path == 1 ? g_low : g_high);
      const float* be = path == 0 ? be_mid : (path == 1 ? be_low : be_high);
      float a = ga[c] * s_iv[path][b][g];
      float bb = be[c] - s_m[path][b][g] * a;
      float mean;
      if (path == 2)
        mean = a * (swsum[r] * invP) + bb;
      else {
        const float* su = path == 0 ? sumM : sumL;
        mean = a * (su[r] * invP) + bb;
      }
      float* Ad = path == 0 ? Am : (path == 1 ? Al : Ah);
      float* Bd = path == 0 ? Bm : (path == 1 ? Bl : Bh);
      Ad[r] = a;
      Bd[r] = bb;
      s_mean[path][b][c] = mean;
    }
  }
  __syncthreads();
  if (tid < 6) {
    int path = tid >> 1, b = tid & 1;
    int active = (path == 0) || (path == 1 && hasLow) || (path == 2 && hasHigh);
    float s = 0.f;
    if (active) {
      float t = 0.f;
      for (int c = 0; c < COUT; c++) t += s_mean[path][b][c] * w_sa[c];
      t += b_sa[0];
      t = fmaxf(t, 0.0f);
      s = fminf(fmaxf(t + 3.f, 0.f), 6.f) * (1.f / 6.f);
      svec[path * NB + b] = s;
    }
    s_s[path][b] = s;
  }
  __syncthreads();
  for (int idx = tid; idx < NB * COUT; idx += 256) {
    int b = idx / COUT, c = idx % COUT;
    float v = s_s[0][b] * s_mean[0][b][c];
    if (hasLow) v += s_s[1][b] * s_mean[1][b][c];
    if (hasHigh) v += s_s[2][b] * s_mean[2][b][c];
    s_nm[b][c] = v * invn;
  }
  __syncthreads();
  if (tid < NB * 64) {
    int b = tid / 64, j = tid % 64;
    float t = b1[j];
    for (int c = 0; c < COUT; c++) t += s_nm[b][c] * w1[j * COUT + c];
    s_h[b][j] = fmaxf(t, 0.f);
  }
  __syncthreads();
  for (int idx = tid; idx < NB * 1024; idx += 256) {
    int b = idx / 1024, i = idx % 1024;
    float t = b2[i];
    for (int j = 0; j < 64; j++) t += s_h[b][j] * w2[i * 64 + j];
    coef[idx] = fminf(fmaxf(t + 3.f, 0.f), 6.f) * (1.f / 6.f) - 0.5f;
  }
}

// ---------------------------------------------------------------------------
// Fused epilogue: GN-affine+scale of mid (+low) (+bilinear-resized high),
// then DyReLU. One pass over the output.
// ---------------------------------------------------------------------------
__global__ __launch_bounds__(256) void fused_apply_kernel(
    const float* __restrict__ featM, const float* __restrict__ featL,
    const float* __restrict__ featH, const float* __restrict__ Am,
    const float* __restrict__ Bm, const float* __restrict__ Al,
    const float* __restrict__ Bl, const float* __restrict__ Ah,
    const float* __restrict__ Bh, const float* __restrict__ svec,
    const float* __restrict__ coef, float* __restrict__ out, int P, int Ho,
    int Hh, int hasLow, int hasHigh, float invn) {
  int idx = blockIdx.x * 256 + threadIdx.x;
  int bc = idx / P, p = idx % P;
  int b = bc / COUT, c = bc % COUT;
  float v = (featM[idx] * Am[bc] + Bm[bc]) * svec[b];
  if (hasLow) v += (featL[idx] * Al[bc] + Bl[bc]) * svec[2 + b];
  if (hasHigh) {
    int Y = p / Ho, X = p % Ho;
    float r = (float)(Hh - 1) / (float)(Ho - 1);
    float sy = (float)Y * r, sx = (float)X * r;
    int yl = (int)floorf(sy), xl = (int)floorf(sx);
    int yh = min(yl + 1, Hh - 1), xh = min(xl + 1, Hh - 1);
    float wy = sy - (float)yl, wx = sx - (float)xl;
    const float* fp = featH + (size_t)bc * Hh * Hh;
    float t0 = fp[yl * Hh + xl] * (1.f - wx) + fp[yl * Hh + xh] * wx;
    float t1 = fp[yh * Hh + xl] * (1.f - wx) + fp[yh * Hh + xh] * wx;
    v += ((t0 * (1.f - wy) + t1 * wy) * Ah[bc] + Bh[bc]) * svec[4 + b];
  }
  float x = v * invn;
  float a1 = coef[b * 1024 + c] * 2.f + 1.f;
  float b1v = coef[b * 1024 + 256 + c];
  float a2 = coef[b * 1024 + 512 + c] * 2.f;
  float b2v = coef[b * 1024 + 768 + c];
  out[idx] = fmaxf(x * a1 + b1v, x * a2 + b2v);
}

// ---------------------------------------------------------------------------
extern "C" void kernel_launch(void* const* d_in, const int* in_sizes, int n_in,
                              void* d_out, int out_size, void* d_ws,
                              size_t ws_size, hipStream_t stream) {
  (void)in_sizes; (void)n_in; (void)out_size; (void)ws_size;
  const float* x[3] = {(const float*)d_in[0], (const float*)d_in[1],
                       (const float*)d_in[2]};
  const float* w_off = (const float*)d_in[3];
  const float* b_off = (const float*)d_in[4];
  const float* w_mid = (const float*)d_in[5];
  const float* g_mid = (const float*)d_in[6];
  const float* be_mid = (const float*)d_in[7];
  const float* w_low = (const float*)d_in[8];
  const float* g_low = (const float*)d_in[9];
  const float* be_low = (const float*)d_in[10];
  const float* w_high = (const float*)d_in[11];
  const float* g_high = (const float*)d_in[12];
  const float* be_high = (const float*)d_in[13];
  const float* w_sa = (const float*)d_in[14];
  const float* b_sa = (const float*)d_in[15];
  const float* w_dy1 = (const float*)d_in[16];
  const float* b_dy1 = (const float*)d_in[17];
  const float* w_dy2 = (const float*)d_in[18];
  const float* b_dy2 = (const float*)d_in[19];

  float* out = (float*)d_out;
  char* wsb = (char*)d_ws;
  size_t o = 0;
  unsigned short* xT0 = (unsigned short*)(wsb + o); o += 16777216;
  unsigned short* xT1 = (unsigned short*)(wsb + o); o += 4194304;
  unsigned short* xT2 = (unsigned short*)(wsb + o); o += 1048576;
  unsigned short* wtm = (unsigned short*)(wsb + o); o += 1179648;
  unsigned short* wtl = (unsigned short*)(wsb + o); o += 1179648;
  unsigned short* wth = (unsigned short*)(wsb + o); o += 1179648;
  unsigned short* wo  = (unsigned short*)(wsb + o); o += 294912;
  float* om0 = (float*)(wsb + o); o += 3538944;
  float* om1 = (float*)(wsb + o); o += 884736;
  float* om2 = (float*)(wsb + o); o += 221184;
  float* arena = (float*)(wsb + o); o += 44040192;
  float* sumM = (float*)(wsb + o); o += 2048;
  float* sqM = (float*)(wsb + o); o += 2048;
  float* sumL = (float*)(wsb + o); o += 2048;
  float* sqL = (float*)(wsb + o); o += 2048;
  float* sumH = (float*)(wsb + o); o += 2048;
  float* sqH = (float*)(wsb + o); o += 2048;
  float* Swsum = (float*)(wsb + o); o += 2048;
  float* Am = (float*)(wsb + o); o += 2048;
  float* Bm = (float*)(wsb + o); o += 2048;
  float* Al = (float*)(wsb + o); o += 2048;
  float* Bl = (float*)(wsb + o); o += 2048;
  float* Ah = (float*)(wsb + o); o += 2048;
  float* Bh = (float*)(wsb + o); o += 2048;
  float* svec = (float*)(wsb + o); o += 64;
  float* dycoef = (float*)(wsb + o); o += 8192;

  // x_lo scratch aliases the feat arena (consumed by conv_offset before
  // any mdconv writes feats).
  unsigned short* xLo0 = (unsigned short*)arena;
  unsigned short* xLo1 = xLo0 + 8388608;
  unsigned short* xLo2 = xLo1 + 2097152;

  const unsigned short* xT[3] = {xT0, xT1, xT2};
  float* om[3] = {om0, om1, om2};

  transpose_kernel<<<dim3(256, 4, NB), 256, 0, stream>>>(x[0], xT0, xLo0, 16384);
  transpose_kernel<<<dim3(64, 4, NB), 256, 0, stream>>>(x[1], xT1, xLo1, 4096);
  transpose_kernel<<<dim3(16, 4, NB), 256, 0, stream>>>(x[2], xT2, xLo2, 1024);
  repack_w_kernel<<<2304, 256, 0, stream>>>(w_mid, wtm);
  repack_w_kernel<<<2304, 256, 0, stream>>>(w_low, wtl);
  repack_w_kernel<<<2304, 256, 0, stream>>>(w_high, wth);
  repack_wo_kernel<<<576, 256, 0, stream>>>(w_off, wo);

  // Batched offset conv over all 3 levels.
  CoB cob;
  cob.L[0] = {xT0, xLo0, om0, 128, 128, 64, 6, 1, 16384};
  cob.L[1] = {xT1, xLo1, om1, 64, 64, 64, 6, 1, 4096};
  cob.L[2] = {xT2, xLo2, om2, 32, 32, 32, 5, 2, 1024};
  cob.off[0] = 0; cob.off[1] = 512; cob.off[2] = 640; cob.off[3] = 672;
  conv_offset_kernel<<<672, 256, 0, stream>>>(cob, wo, b_off);

  const int Hs[3] = {128, 64, 32};
  const size_t outOff[3] = {0, 8388608, 10485760};
  const int nterm[3] = {2, 3, 2};

  for (int l = 0; l < 3; l++) {
    int H = Hs[l];
    int P = H * H;
    int hasLow = (l > 0), hasHigh = (l < 2);
    int Hh = H / 2, Ph = Hh * Hh;
    float* outl = out + outOff[l];
    float* featM = arena;
    float* featL = arena + (size_t)512 * P;
    float* featH = arena + (size_t)(hasLow ? 1024 : 512) * P;

    MdBatch mb;
    mb.om = om[l];
    mb.omW = H;
    mb.omP = P;
    int nMid = (P / 64) * NB;
    mb.p[0] = {xT[l], wtm, featM, H, H, H, H, 1, 1, P / 64};
    int total = nMid;
    int idx = 1;
    if (hasLow) {
      int Hp = Hs[l - 1];
      mb.p[idx] = {xT[l - 1], wtl, featL, Hp, Hp, H, H, 2, 1, P / 64};
      idx++;
      total += nMid;
    }
    if (hasHigh) {
      mb.p[idx] = {xT[l + 1], wth, featH, Hh, Hh, Hh, Hh, 1, 2, Ph / 64};
      idx++;
      total += (Ph / 64) * NB;
    }
    // offsets for path decode
    mb.off[0] = 0;
    if (l == 0) {            // mid, high
      mb.off[1] = nMid; mb.off[2] = total; mb.off[3] = total;
      mb.p[2] = mb.p[1];
    } else if (l == 1) {     // mid, low, high
      mb.off[1] = nMid; mb.off[2] = 2 * nMid; mb.off[3] = total;
    } else {                 // mid, low
      mb.off[1] = nMid; mb.off[2] = total; mb.off[3] = total;
      mb.p[2] = mb.p[1];
    }
    mdconv_kernel<<<total, 256, 0, stream>>>(mb);

    chanstats_kernel<<<dim3(COUT, NB), 256, 0, stream>>>(featM, P, sumM, sqM);
    if (hasLow)
      chanstats_kernel<<<dim3(COUT, NB), 256, 0, stream>>>(featL, P, sumL, sqL);
    if (hasHigh)
      chanstats3_kernel<<<dim3(COUT, NB), 256, 0, stream>>>(featH, Ph, Hh, H,
                                                            sumH, sqH, Swsum);

    prep_all_kernel<<<1, 256, 0, stream>>>(
        sumM, sqM, sumL, sqL, sumH, sqH, Swsum, g_mid, be_mid, g_low, be_low,
        g_high, be_high, w_sa, b_sa, w_dy1, b_dy1, w_dy2, b_dy2, 1.0f / P,
        1.0f / Ph, hasLow, hasHigh, 1.0f / nterm[l], Am, Bm, Al, Bl, Ah, Bh,
        svec, dycoef);

    fused_apply_kernel<<<(NB * COUT * P) / 256, 256, 0, stream>>>(
        featM, featL, featH, Am, Bm, Al, Bl, Ah, Bh, svec, dycoef, outl, P, H,
        Hh, hasLow, hasHigh, 1.0f / nterm[l]);
  }
}

// Round 5
// 693.396 us; speedup vs baseline: 14.3750x; 1.0081x over previous
//
#include <hip/hip_runtime.h>
#include <hip/hip_bf16.h>
#include <math.h>

#define CIN 256
#define COUT 256
#define NB 2
#define GN_GROUPS 16

typedef __attribute__((ext_vector_type(8))) short short8;
typedef __attribute__((ext_vector_type(4))) float floatx4;

__device__ __forceinline__ float b2f(unsigned short u) {
  union { unsigned int i; float f; } v;
  v.i = ((unsigned int)u) << 16;
  return v.f;
}
__device__ __forceinline__ unsigned short f2b(float f) {
  union { float f; unsigned int i; } v;
  v.f = f;
  unsigned int r = (v.i + 0x7FFFu + ((v.i >> 16) & 1u)) >> 16;
  return (unsigned short)r;
}
__device__ __forceinline__ float lo2f(unsigned int u) {
  union { unsigned int i; float f; } v;
  v.i = u << 16;
  return v.f;
}
__device__ __forceinline__ float hi2f(unsigned int u) {
  union { unsigned int i; float f; } v;
  v.i = u & 0xffff0000u;
  return v.f;
}
__device__ __forceinline__ unsigned int pk2(float a, float b) {
  union { __hip_bfloat162 h; unsigned int u; } v;
  v.h = __float22bfloat162_rn(float2{a, b});
  return v.u;
}

// ---------------------------------------------------------------------------
// NCHW fp32 -> NHWC bf16 hi + residual lo, one pass. grid (P/64, 4, B).
// ---------------------------------------------------------------------------
__global__ __launch_bounds__(256) void transpose_kernel(
    const float* __restrict__ x, unsigned short* __restrict__ xT,
    unsigned short* __restrict__ xLo, int P) {
  __shared__ float tile[64][65];
  int pBase = blockIdx.x * 64, cBase = blockIdx.y * 64, b = blockIdx.z;
  int t = threadIdx.x;
  int pl = t & 63, ch = t >> 6;
  const float* xb = x + ((size_t)b * CIN + cBase) * P + pBase;
#pragma unroll
  for (int e = 0; e < 16; e++) {
    int c = ch * 16 + e;
    tile[c][pl] = xb[(size_t)c * P + pl];
  }
  __syncthreads();
  size_t obase = ((size_t)b * P + pBase) * CIN + cBase;
  int cl = t & 63, pr = t >> 6;
#pragma unroll
  for (int e = 0; e < 16; e++) {
    int p = pr * 16 + e;
    float v = tile[cl][p];
    unsigned short h = f2b(v);
    xT[obase + (size_t)p * CIN + cl] = h;
    xLo[obase + (size_t)p * CIN + cl] = f2b(v - b2f(h));
  }
}

// ---------------------------------------------------------------------------
// Repack mdconv weight (256,256,3,3) fp32 -> bf16 [oc][K], K = tap*256 + c
// ---------------------------------------------------------------------------
__global__ void repack_w_kernel(const float* __restrict__ w,
                                unsigned short* __restrict__ wt) {
  int idx = blockIdx.x * 256 + threadIdx.x;  // 589824
  int oc = idx / 2304, kk = idx % 2304;
  int k = kk >> 8, c = kk & 255;
  wt[idx] = f2b(w[(size_t)oc * 2304 + c * 9 + k]);
}

// Offset-conv weight (27,256,3,3) -> bf16 wo[sel][tap][cb][oc32][ch32]
__global__ void repack_wo_kernel(const float* __restrict__ w,
                                 unsigned short* __restrict__ wo) {
  int idx = blockIdx.x * 256 + threadIdx.x;  // 2*73728
  int sel = idx / 73728;
  int r = idx % 73728;
  int k = r / 8192;
  int r2 = r % 8192;
  int cbk = r2 / 1024;
  int oc = (r2 / 32) % 32;
  int ch = r2 % 32;
  int c = cbk * 32 + ch;
  float val = (oc < 27) ? w[(size_t)oc * 2304 + c * 9 + k] : 0.0f;
  float hi = b2f(f2b(val));
  wo[idx] = sel ? f2b(val - hi) : f2b(val);
}

// ---------------------------------------------------------------------------
// Offset conv: halo-staged LDS + MFMA, split-bf16, batched over levels.
// ---------------------------------------------------------------------------
struct CoL {
  const unsigned short* xhi;
  const unsigned short* xlo;
  float* om;
  int H, W, Cs, cshift, Rs, P;
};
struct CoB { CoL L[3]; int off[4]; };

__global__ __launch_bounds__(256) void conv_offset_kernel(
    CoB B, const unsigned short* __restrict__ wo,
    const float* __restrict__ bias) {
  __shared__ unsigned short s_hi[204 * 40];
  __shared__ unsigned short s_lo[204 * 40];
  int bx = blockIdx.x;
  int li = (bx >= B.off[1] ? 1 : 0) + (bx >= B.off[2] ? 1 : 0);
  CoL L = B.L[li];
  int local = bx - B.off[li];
  int tpb = L.P / 64;
  int b = local / tpb, pxt = local % tpb;
  int t = threadIdx.x;
  int pbase = pxt * 64;
  int r0 = pbase / L.W;
  int c0 = pbase % L.W;
  int Ct = L.Cs + 2;
  int Npos = Ct * (L.Rs + 2);
  const unsigned short* xhib = L.xhi + (size_t)b * L.P * CIN;
  const unsigned short* xlob = L.xlo + (size_t)b * L.P * CIN;

  int lane = t & 63, wv = t >> 6, quad = lane >> 4, ln = lane & 15;
  int pl = wv * 16 + ln;
  int pi_ = pl >> L.cshift;
  int pj_ = pl & (L.Cs - 1);

  floatx4 acc0 = {0.f, 0.f, 0.f, 0.f}, acc1 = {0.f, 0.f, 0.f, 0.f};

  for (int cb = 0; cb < 8; cb++) {
    __syncthreads();
    for (int e = t; e < Npos * 4; e += 256) {
      int pos = e >> 2, oct = e & 3;
      int r = pos / Ct, c = pos % Ct;
      int gy = r0 - 1 + r, gx = c0 - 1 + c;
      uint4 vhi = {0, 0, 0, 0}, vlo = {0, 0, 0, 0};
      if (gy >= 0 && gy < L.H && gx >= 0 && gx < L.W) {
        size_t off = ((size_t)(gy * L.W + gx)) * CIN + cb * 32 + oct * 8;
        vhi = *(const uint4*)(xhib + off);
        vlo = *(const uint4*)(xlob + off);
      }
      *(uint4*)&s_hi[pos * 40 + oct * 8] = vhi;
      *(uint4*)&s_lo[pos * 40 + oct * 8] = vlo;
    }
    __syncthreads();
#pragma unroll
    for (int tap = 0; tap < 9; tap++) {
      int dy = tap / 3 - 1, dx = tap % 3 - 1;
      const unsigned short* wb0 = wo + (size_t)((0 * 9 + tap) * 8 + cb) * 1024;
      const unsigned short* wb1 = wo + (size_t)((1 * 9 + tap) * 8 + cb) * 1024;
      short8 whi0 = *(const short8*)(wb0 + ln * 32 + quad * 8);
      short8 whi1 = *(const short8*)(wb0 + (16 + ln) * 32 + quad * 8);
      short8 wlo0 = *(const short8*)(wb1 + ln * 32 + quad * 8);
      short8 wlo1 = *(const short8*)(wb1 + (16 + ln) * 32 + quad * 8);
      int pos = (pi_ + dy + 1) * Ct + (pj_ + dx + 1);
      short8 bhi = *(const short8*)&s_hi[pos * 40 + quad * 8];
      short8 blo = *(const short8*)&s_lo[pos * 40 + quad * 8];
      acc0 = __builtin_amdgcn_mfma_f32_16x16x32_bf16(whi0, bhi, acc0, 0, 0, 0);
      acc1 = __builtin_amdgcn_mfma_f32_16x16x32_bf16(whi1, bhi, acc1, 0, 0, 0);
      acc0 = __builtin_amdgcn_mfma_f32_16x16x32_bf16(wlo0, bhi, acc0, 0, 0, 0);
      acc1 = __builtin_amdgcn_mfma_f32_16x16x32_bf16(wlo1, bhi, acc1, 0, 0, 0);
      acc0 = __builtin_amdgcn_mfma_f32_16x16x32_bf16(whi0, blo, acc0, 0, 0, 0);
      acc1 = __builtin_amdgcn_mfma_f32_16x16x32_bf16(whi1, blo, acc1, 0, 0, 0);
    }
  }

  int px = pbase + pl;
#pragma unroll
  for (int i2 = 0; i2 < 2; i2++) {
#pragma unroll
    for (int r = 0; r < 4; r++) {
      int oc = i2 * 16 + quad * 4 + r;
      if (oc < 27) {
        float val = (i2 == 0 ? acc0[r] : acc1[r]) + bias[oc];
        if (oc >= 18) val = 1.f / (1.f + __expf(-val));
        L.om[((size_t)b * 27 + oc) * L.P + px] = val;
      }
    }
  }
}

// ---------------------------------------------------------------------------
// Modulated deformable conv v4: weights direct-from-global (L2-hot) in MFMA
// fragment layout (no LDS weight staging), double-buffered col tile, one
// barrier per K-chunk, XCD-banded tile swizzle, fused GN/resize stats via
// wave-reduce + atomics. Batched over a level's paths.
// ---------------------------------------------------------------------------
struct MdP {
  const unsigned short* xT;
  const unsigned short* wt;
  float* outf;
  const float* om;
  float* sum;
  float* sumsq;
  float* wsum;  // non-null for high path
  int Hi, Wi, Wo, lWo, stride, omStep, omW, omP, ltile, Hro;
};
struct MdBatch { MdP p[3]; int off[4]; };

__global__ __launch_bounds__(256, 3) void mdconv_kernel(MdBatch B) {
  __shared__ float4 s_cw[9][64];
  __shared__ int s_yy[9][64];
  __shared__ int s_xx[9][64];
  __shared__ unsigned short s_col[2][64][40];
  __shared__ float s_prof[64];

  int bx = blockIdx.x;
  int pidx = (bx >= B.off[1] ? 1 : 0) + (bx >= B.off[2] ? 1 : 0);
  MdP P = B.p[pidx];
  int local = bx - B.off[pidx];
  // XCD banding: consecutive bx round-robin XCDs; give each XCD a
  // contiguous band of tiles for L2 locality.
  int ntile = 1 << P.ltile;
  int nslots = (NB << P.ltile) >> 3;
  int flat = (local & 7) * nslots + (local >> 3);
  int b = flat >> P.ltile;
  int pxt = flat & (ntile - 1);
  int Po = P.Wo << P.lWo;
  const unsigned short* xTb = P.xT + (size_t)b * P.Hi * P.Wi * CIN;

  int t = threadIdx.x;
  // resize weight profile (high path only; wave-uniform branch)
  if (P.wsum) {
    if (t < P.Wo) s_prof[t] = 0.f;
    __syncthreads();
    if (t < P.Hro) {
      float r = (float)(P.Wo - 1) / (float)(P.Hro - 1);
      float sy = (float)t * r;
      int yl = (int)floorf(sy);
      float fy = sy - (float)yl;
      int yh = min(yl + 1, P.Wo - 1);
      atomicAdd(&s_prof[yl], 1.f - fy);
      atomicAdd(&s_prof[yh], fy);
    }
  }
  // Phase 0: sampling metadata for 9 taps x 64 px
  for (int e = t; e < 576; e += 256) {
    int k = e / 64, px = e % 64;
    int p = pxt * 64 + px;
    int i = p >> P.lWo, j = p & (P.Wo - 1);
    int pc = (i * P.omStep) * B.p[pidx].omW + j * P.omStep;
    const float* omb = P.om + (size_t)b * 27 * P.omP;
    float offy = omb[(size_t)(2 * k) * P.omP + pc];
    float offx = omb[(size_t)(2 * k + 1) * P.omP + pc];
    float m = omb[(size_t)(18 + k) * P.omP + pc];
    float py = (float)(i * P.stride) - 1.0f + (float)(k / 3) + offy;
    float pxf = (float)(j * P.stride) - 1.0f + (float)(k % 3) + offx;
    float y0f = floorf(py), x0f = floorf(pxf);
    float wy = py - y0f, wx = pxf - x0f;
    int y0 = (int)y0f, x0 = (int)x0f;
    int y1 = y0 + 1, x1 = x0 + 1;
    float vy0 = (y0 >= 0 && y0 < P.Hi) ? 1.f : 0.f;
    float vy1 = (y1 >= 0 && y1 < P.Hi) ? 1.f : 0.f;
    float vx0 = (x0 >= 0 && x0 < P.Wi) ? 1.f : 0.f;
    float vx1 = (x1 >= 0 && x1 < P.Wi) ? 1.f : 0.f;
    float4 cw;
    cw.x = (1.f - wy) * (1.f - wx) * m * vy0 * vx0;
    cw.y = (1.f - wy) * wx * m * vy0 * vx1;
    cw.z = wy * (1.f - wx) * m * vy1 * vx0;
    cw.w = wy * wx * m * vy1 * vx1;
    s_cw[k][px] = cw;
    int y0c = min(max(y0, 0), P.Hi - 1), y1c = min(max(y1, 0), P.Hi - 1);
    int x0c = min(max(x0, 0), P.Wi - 1), x1c = min(max(x1, 0), P.Wi - 1);
    s_yy[k][px] = y0c | (y1c << 16);
    s_xx[k][px] = x0c | (x1c << 16);
  }
  __syncthreads();

  floatx4 acc[4][4];
#pragma unroll
  for (int i = 0; i < 4; i++)
#pragma unroll
    for (int j = 0; j < 4; j++) acc[i][j] = (floatx4){0.f, 0.f, 0.f, 0.f};

  int lane = t & 63, wv = t >> 6;
  int quad = lane >> 4, ln = lane & 15;
  int wOc = wv * 64;
  int gpx = t >> 2, goct = t & 3;  // gather item: (px, 8-ch octet)

  uint4 greg[4];

  // prologue: gather + stage chunk 0 into buf 0
  {
    int yy = s_yy[0][gpx], xx = s_xx[0][gpx];
    int y0 = yy & 0xffff, y1 = (yy >> 16) & 0xffff;
    int x0 = xx & 0xffff, x1 = (xx >> 16) & 0xffff;
    const unsigned short* base = xTb + goct * 8;
    greg[0] = *(const uint4*)(base + (size_t)(y0 * P.Wi + x0) * CIN);
    greg[1] = *(const uint4*)(base + (size_t)(y0 * P.Wi + x1) * CIN);
    greg[2] = *(const uint4*)(base + (size_t)(y1 * P.Wi + x0) * CIN);
    greg[3] = *(const uint4*)(base + (size_t)(y1 * P.Wi + x1) * CIN);
    float4 cw = s_cw[0][gpx];
    float r[8];
#pragma unroll
    for (int j = 0; j < 4; j++) {
      unsigned int a = ((unsigned int*)&greg[0])[j];
      unsigned int bb = ((unsigned int*)&greg[1])[j];
      unsigned int c = ((unsigned int*)&greg[2])[j];
      unsigned int d = ((unsigned int*)&greg[3])[j];
      r[2 * j] = cw.x * lo2f(a) + cw.y * lo2f(bb) + cw.z * lo2f(c) + cw.w * lo2f(d);
      r[2 * j + 1] = cw.x * hi2f(a) + cw.y * hi2f(bb) + cw.z * hi2f(c) + cw.w * hi2f(d);
    }
    uint4 packed;
    packed.x = pk2(r[0], r[1]);
    packed.y = pk2(r[2], r[3]);
    packed.z = pk2(r[4], r[5]);
    packed.w = pk2(r[6], r[7]);
    *(uint4*)&s_col[0][gpx][goct * 8] = packed;
  }
  __syncthreads();

  for (int kc = 0; kc < 72; kc++) {
    int cur = kc & 1, nxt = cur ^ 1;
    int kn = kc + 1;
    if (kn < 72) {
      int k = kn >> 3, cbk = kn & 7;
      int yy = s_yy[k][gpx], xx = s_xx[k][gpx];
      int y0 = yy & 0xffff, y1 = (yy >> 16) & 0xffff;
      int x0 = xx & 0xffff, x1 = (xx >> 16) & 0xffff;
      const unsigned short* base = xTb + cbk * 32 + goct * 8;
      greg[0] = *(const uint4*)(base + (size_t)(y0 * P.Wi + x0) * CIN);
      greg[1] = *(const uint4*)(base + (size_t)(y0 * P.Wi + x1) * CIN);
      greg[2] = *(const uint4*)(base + (size_t)(y1 * P.Wi + x0) * CIN);
      greg[3] = *(const uint4*)(base + (size_t)(y1 * P.Wi + x1) * CIN);
    }
    // A-frags direct from global (wt is L2-hot), exact fragment layout
    int kBase = (kc >> 3) * 256 + (kc & 7) * 32;
    short8 af[4], bfr[4];
#pragma unroll
    for (int i = 0; i < 4; i++)
      af[i] = *(const short8*)(P.wt + (size_t)(wOc + i * 16 + ln) * 2304 +
                               kBase + quad * 8);
#pragma unroll
    for (int j = 0; j < 4; j++)
      bfr[j] = *(const short8*)&s_col[cur][j * 16 + ln][quad * 8];
#pragma unroll
    for (int i = 0; i < 4; i++)
#pragma unroll
      for (int j = 0; j < 4; j++)
        acc[i][j] = __builtin_amdgcn_mfma_f32_16x16x32_bf16(af[i], bfr[j],
                                                            acc[i][j], 0, 0, 0);
    if (kn < 72) {
      float4 cw = s_cw[kn >> 3][gpx];
      float r[8];
#pragma unroll
      for (int j = 0; j < 4; j++) {
        unsigned int a = ((unsigned int*)&greg[0])[j];
        unsigned int bb = ((unsigned int*)&greg[1])[j];
        unsigned int c = ((unsigned int*)&greg[2])[j];
        unsigned int d = ((unsigned int*)&greg[3])[j];
        r[2 * j] = cw.x * lo2f(a) + cw.y * lo2f(bb) + cw.z * lo2f(c) + cw.w * lo2f(d);
        r[2 * j + 1] = cw.x * hi2f(a) + cw.y * hi2f(bb) + cw.z * hi2f(c) + cw.w * hi2f(d);
      }
      uint4 packed;
      packed.x = pk2(r[0], r[1]);
      packed.y = pk2(r[2], r[3]);
      packed.z = pk2(r[4], r[5]);
      packed.w = pk2(r[6], r[7]);
      *(uint4*)&s_col[nxt][gpx][goct * 8] = packed;
    }
    __syncthreads();
  }

  // epilogue: store C (col=lane&15 -> px, row=(lane>>4)*4+reg -> oc)
#pragma unroll
  for (int i = 0; i < 4; i++) {
    int ocB = wOc + i * 16 + quad * 4;
#pragma unroll
    for (int j = 0; j < 4; j++) {
      int px = pxt * 64 + j * 16 + ln;
#pragma unroll
      for (int r = 0; r < 4; r++)
        P.outf[((size_t)b * COUT + ocB + r) * Po + px] = acc[i][j][r];
    }
  }

  // fused stats: per-oc sum / sumsq (+ resize-weighted sum for high path)
  float pw[4];
  if (P.wsum) {
#pragma unroll
    for (int j = 0; j < 4; j++) {
      int px = pxt * 64 + j * 16 + ln;
      pw[j] = s_prof[px >> P.lWo] * s_prof[px & (P.Wo - 1)];
    }
  }
#pragma unroll
  for (int i = 0; i < 4; i++) {
    int ocB = wOc + i * 16 + quad * 4;
#pragma unroll
    for (int r = 0; r < 4; r++) {
      float s1 = 0.f, s2 = 0.f, sw = 0.f;
#pragma unroll
      for (int j = 0; j < 4; j++) {
        float v = acc[i][j][r];
        s1 += v;
        s2 += v * v;
        if (P.wsum) sw += v * pw[j];
      }
#pragma unroll
      for (int m = 1; m < 16; m <<= 1) {
        s1 += __shfl_xor(s1, m, 64);
        s2 += __shfl_xor(s2, m, 64);
        if (P.wsum) sw += __shfl_xor(sw, m, 64);
      }
      if (ln == 0) {
        atomicAdd(&P.sum[b * COUT + ocB + r], s1);
        atomicAdd(&P.sumsq[b * COUT + ocB + r], s2);
        if (P.wsum) atomicAdd(&P.wsum[b * COUT + ocB + r], sw);
      }
    }
  }
}

// ---------------------------------------------------------------------------
// All per-level scalar prep (GN affines, attention scalars, DyReLU MLP).
// ---------------------------------------------------------------------------
__global__ __launch_bounds__(256) void prep_all_kernel(
    const float* __restrict__ sumM, const float* __restrict__ sqM,
    const float* __restrict__ sumL, const float* __restrict__ sqL,
    const float* __restrict__ sumH, const float* __restrict__ sqH,
    const float* __restrict__ swsum, const float* __restrict__ g_mid,
    const float* __restrict__ be_mid, const float* __restrict__ g_low,
    const float* __restrict__ be_low, const float* __restrict__ g_high,
    const float* __restrict__ be_high, const float* __restrict__ w_sa,
    const float* __restrict__ b_sa, const float* __restrict__ w1,
    const float* __restrict__ b1, const float* __restrict__ w2,
    const float* __restrict__ b2, float invP, float invPh, int hasLow,
    int hasHigh, float invn, float* __restrict__ Am, float* __restrict__ Bm,
    float* __restrict__ Al, float* __restrict__ Bl, float* __restrict__ Ah,
    float* __restrict__ Bh, float* __restrict__ svec,
    float* __restrict__ coef) {
  __shared__ float s_m[3][NB][GN_GROUPS], s_iv[3][NB][GN_GROUPS];
  __shared__ float s_mean[3][NB][COUT];
  __shared__ float s_s[3][NB];
  __shared__ float s_nm[NB][COUT];
  __shared__ float s_h[NB][64];
  int tid = threadIdx.x;

  if (tid < 96) {
    int path = tid / 32, b = (tid >> 4) & 1, g = tid & 15;
    int active = (path == 0) || (path == 1 && hasLow) || (path == 2 && hasHigh);
    if (active) {
      const float* su = path == 0 ? sumM : (path == 1 ? sumL : sumH);
      const float* sq = path == 0 ? sqM : (path == 1 ? sqL : sqH);
      float invN = ((path == 2) ? invPh : invP) * (1.f / 16.f);
      float s = 0.f, q = 0.f;
      for (int c = g * 16; c < g * 16 + 16; c++) {
        s += su[b * COUT + c];
        q += sq[b * COUT + c];
      }
      float m = s * invN;
      float v = q * invN - m * m;
      s_m[path][b][g] = m;
      s_iv[path][b][g] = rsqrtf(v + 1e-5f);
    }
  }
  __syncthreads();
  for (int idx = tid; idx < 3 * NB * COUT; idx += 256) {
    int path = idx / (NB * COUT);
    int r = idx % (NB * COUT);
    int b = r / COUT, c = r % COUT, g = c >> 4;
    int active = (path == 0) || (path == 1 && hasLow) || (path == 2 && hasHigh);
    if (active) {
      const float* ga = path == 0 ? g_mid : (path == 1 ? g_low : g_high);
      const float* be = path == 0 ? be_mid : (path == 1 ? be_low : be_high);
      float a = ga[c] * s_iv[path][b][g];
      float bb = be[c] - s_m[path][b][g] * a;
      float mean;
      if (path == 2)
        mean = a * (swsum[r] * invP) + bb;
      else {
        const float* su = path == 0 ? sumM : sumL;
        mean = a * (su[r] * invP) + bb;
      }
      float* Ad = path == 0 ? Am : (path == 1 ? Al : Ah);
      float* Bd = path == 0 ? Bm : (path == 1 ? Bl : Bh);
      Ad[r] = a;
      Bd[r] = bb;
      s_mean[path][b][c] = mean;
    }
  }
  __syncthreads();
  if (tid < 6) {
    int path = tid >> 1, b = tid & 1;
    int active = (path == 0) || (path == 1 && hasLow) || (path == 2 && hasHigh);
    float s = 0.f;
    if (active) {
      float t = 0.f;
      for (int c = 0; c < COUT; c++) t += s_mean[path][b][c] * w_sa[c];
      t += b_sa[0];
      t = fmaxf(t, 0.0f);
      s = fminf(fmaxf(t + 3.f, 0.f), 6.f) * (1.f / 6.f);
      svec[path * NB + b] = s;
    }
    s_s[path][b] = s;
  }
  __syncthreads();
  for (int idx = tid; idx < NB * COUT; idx += 256) {
    int b = idx / COUT, c = idx % COUT;
    float v = s_s[0][b] * s_mean[0][b][c];
    if (hasLow) v += s_s[1][b] * s_mean[1][b][c];
    if (hasHigh) v += s_s[2][b] * s_mean[2][b][c];
    s_nm[b][c] = v * invn;
  }
  __syncthreads();
  if (tid < NB * 64) {
    int b = tid / 64, j = tid % 64;
    float t = b1[j];
    for (int c = 0; c < COUT; c++) t += s_nm[b][c] * w1[j * COUT + c];
    s_h[b][j] = fmaxf(t, 0.f);
  }
  __syncthreads();
  for (int idx = tid; idx < NB * 1024; idx += 256) {
    int b = idx / 1024, i = idx % 1024;
    float t = b2[i];
    for (int j = 0; j < 64; j++) t += s_h[b][j] * w2[i * 64 + j];
    coef[idx] = fminf(fmaxf(t + 3.f, 0.f), 6.f) * (1.f / 6.f) - 0.5f;
  }
}

// ---------------------------------------------------------------------------
// Fused epilogue: GN-affine+scale of mid (+low) (+bilinear-resized high),
// then DyReLU. One pass over the output.
// ---------------------------------------------------------------------------
__global__ __launch_bounds__(256) void fused_apply_kernel(
    const float* __restrict__ featM, const float* __restrict__ featL,
    const float* __restrict__ featH, const float* __restrict__ Am,
    const float* __restrict__ Bm, const float* __restrict__ Al,
    const float* __restrict__ Bl, const float* __restrict__ Ah,
    const float* __restrict__ Bh, const float* __restrict__ svec,
    const float* __restrict__ coef, float* __restrict__ out, int P, int Ho,
    int Hh, int hasLow, int hasHigh, float invn) {
  int idx = blockIdx.x * 256 + threadIdx.x;
  int bc = idx / P, p = idx % P;
  int b = bc / COUT, c = bc % COUT;
  float v = (featM[idx] * Am[bc] + Bm[bc]) * svec[b];
  if (hasLow) v += (featL[idx] * Al[bc] + Bl[bc]) * svec[2 + b];
  if (hasHigh) {
    int Y = p / Ho, X = p % Ho;
    float r = (float)(Hh - 1) / (float)(Ho - 1);
    float sy = (float)Y * r, sx = (float)X * r;
    int yl = (int)floorf(sy), xl = (int)floorf(sx);
    int yh = min(yl + 1, Hh - 1), xh = min(xl + 1, Hh - 1);
    float wy = sy - (float)yl, wx = sx - (float)xl;
    const float* fp = featH + (size_t)bc * Hh * Hh;
    float t0 = fp[yl * Hh + xl] * (1.f - wx) + fp[yl * Hh + xh] * wx;
    float t1 = fp[yh * Hh + xl] * (1.f - wx) + fp[yh * Hh + xh] * wx;
    v += ((t0 * (1.f - wy) + t1 * wy) * Ah[bc] + Bh[bc]) * svec[4 + b];
  }
  float x = v * invn;
  float a1 = coef[b * 1024 + c] * 2.f + 1.f;
  float b1v = coef[b * 1024 + 256 + c];
  float a2 = coef[b * 1024 + 512 + c] * 2.f;
  float b2v = coef[b * 1024 + 768 + c];
  out[idx] = fmaxf(x * a1 + b1v, x * a2 + b2v);
}

// ---------------------------------------------------------------------------
extern "C" void kernel_launch(void* const* d_in, const int* in_sizes, int n_in,
                              void* d_out, int out_size, void* d_ws,
                              size_t ws_size, hipStream_t stream) {
  (void)in_sizes; (void)n_in; (void)out_size; (void)ws_size;
  const float* x[3] = {(const float*)d_in[0], (const float*)d_in[1],
                       (const float*)d_in[2]};
  const float* w_off = (const float*)d_in[3];
  const float* b_off = (const float*)d_in[4];
  const float* w_mid = (const float*)d_in[5];
  const float* g_mid = (const float*)d_in[6];
  const float* be_mid = (const float*)d_in[7];
  const float* w_low = (const float*)d_in[8];
  const float* g_low = (const float*)d_in[9];
  const float* be_low = (const float*)d_in[10];
  const float* w_high = (const float*)d_in[11];
  const float* g_high = (const float*)d_in[12];
  const float* be_high = (const float*)d_in[13];
  const float* w_sa = (const float*)d_in[14];
  const float* b_sa = (const float*)d_in[15];
  const float* w_dy1 = (const float*)d_in[16];
  const float* b_dy1 = (const float*)d_in[17];
  const float* w_dy2 = (const float*)d_in[18];
  const float* b_dy2 = (const float*)d_in[19];

  float* out = (float*)d_out;
  char* wsb = (char*)d_ws;
  size_t o = 0;
  unsigned short* xT0 = (unsigned short*)(wsb + o); o += 16777216;
  unsigned short* xT1 = (unsigned short*)(wsb + o); o += 4194304;
  unsigned short* xT2 = (unsigned short*)(wsb + o); o += 1048576;
  unsigned short* wtm = (unsigned short*)(wsb + o); o += 1179648;
  unsigned short* wtl = (unsigned short*)(wsb + o); o += 1179648;
  unsigned short* wth = (unsigned short*)(wsb + o); o += 1179648;
  unsigned short* wo  = (unsigned short*)(wsb + o); o += 294912;
  float* om0 = (float*)(wsb + o); o += 3538944;
  float* om1 = (float*)(wsb + o); o += 884736;
  float* om2 = (float*)(wsb + o); o += 221184;
  float* arena = (float*)(wsb + o); o += 44040192;
  float* stats = (float*)(wsb + o); o += 14336;  // 3584 floats
  float* Am = (float*)(wsb + o); o += 2048;
  float* Bm = (float*)(wsb + o); o += 2048;
  float* Al = (float*)(wsb + o); o += 2048;
  float* Bl = (float*)(wsb + o); o += 2048;
  float* Ah = (float*)(wsb + o); o += 2048;
  float* Bh = (float*)(wsb + o); o += 2048;
  float* svec = (float*)(wsb + o); o += 64;
  float* dycoef = (float*)(wsb + o); o += 8192;

  float* sumM = stats;
  float* sqM = stats + 512;
  float* sumL = stats + 1024;
  float* sqL = stats + 1536;
  float* sumH = stats + 2048;
  float* sqH = stats + 2560;
  float* Swsum = stats + 3072;

  // x_lo scratch aliases the feat arena (consumed by conv_offset before
  // any mdconv writes feats).
  unsigned short* xLo0 = (unsigned short*)arena;
  unsigned short* xLo1 = xLo0 + 8388608;
  unsigned short* xLo2 = xLo1 + 2097152;

  const unsigned short* xT[3] = {xT0, xT1, xT2};
  float* om[3] = {om0, om1, om2};

  transpose_kernel<<<dim3(256, 4, NB), 256, 0, stream>>>(x[0], xT0, xLo0, 16384);
  transpose_kernel<<<dim3(64, 4, NB), 256, 0, stream>>>(x[1], xT1, xLo1, 4096);
  transpose_kernel<<<dim3(16, 4, NB), 256, 0, stream>>>(x[2], xT2, xLo2, 1024);
  repack_w_kernel<<<2304, 256, 0, stream>>>(w_mid, wtm);
  repack_w_kernel<<<2304, 256, 0, stream>>>(w_low, wtl);
  repack_w_kernel<<<2304, 256, 0, stream>>>(w_high, wth);
  repack_wo_kernel<<<576, 256, 0, stream>>>(w_off, wo);

  // Batched offset conv over all 3 levels.
  CoB cob;
  cob.L[0] = {xT0, xLo0, om0, 128, 128, 64, 6, 1, 16384};
  cob.L[1] = {xT1, xLo1, om1, 64, 64, 64, 6, 1, 4096};
  cob.L[2] = {xT2, xLo2, om2, 32, 32, 32, 5, 2, 1024};
  cob.off[0] = 0; cob.off[1] = 512; cob.off[2] = 640; cob.off[3] = 672;
  conv_offset_kernel<<<672, 256, 0, stream>>>(cob, wo, b_off);

  const int Hs[3] = {128, 64, 32};
  const int lHs[3] = {7, 6, 5};
  const size_t outOff[3] = {0, 8388608, 10485760};
  const int nterm[3] = {2, 3, 2};

  for (int l = 0; l < 3; l++) {
    int H = Hs[l];
    int P = H * H;
    int hasLow = (l > 0), hasHigh = (l < 2);
    int Hh = H / 2, Ph = Hh * Hh;
    float* outl = out + outOff[l];
    float* featM = arena;
    float* featL = arena + (size_t)512 * P;
    float* featH = arena + (size_t)(hasLow ? 1024 : 512) * P;

    hipMemsetAsync(stats, 0, 3584 * sizeof(float), stream);

    MdBatch mb;
    int lt = lHs[l] * 2 - 6;  // log2(P/64): 8, 6, 4
    int nMid = (P / 64) * NB;
    mb.p[0] = {xT[l], wtm, featM, om[l], sumM, sqM, nullptr,
               H, H, H, lHs[l], 1, 1, H, P, lt, 0};
    int total = nMid;
    int idx = 1;
    if (hasLow) {
      int Hp = Hs[l - 1];
      mb.p[idx] = {xT[l - 1], wtl, featL, om[l], sumL, sqL, nullptr,
                   Hp, Hp, H, lHs[l], 2, 1, H, P, lt, 0};
      idx++;
      total += nMid;
    }
    if (hasHigh) {
      mb.p[idx] = {xT[l + 1], wth, featH, om[l], sumH, sqH, Swsum,
                   Hh, Hh, Hh, lHs[l] - 1, 1, 2, H, P, lt - 2, H};
      idx++;
      total += (Ph / 64) * NB;
    }
    mb.off[0] = 0;
    if (l == 0) {            // mid, high
      mb.off[1] = nMid; mb.off[2] = 0x7fffffff; mb.off[3] = 0x7fffffff;
      mb.p[2] = mb.p[1];
    } else if (l == 1) {     // mid, low, high
      mb.off[1] = nMid; mb.off[2] = 2 * nMid; mb.off[3] = 0x7fffffff;
    } else {                 // mid, low
      mb.off[1] = nMid; mb.off[2] = 0x7fffffff; mb.off[3] = 0x7fffffff;
      mb.p[2] = mb.p[1];
    }
    mdconv_kernel<<<total, 256, 0, stream>>>(mb);

    prep_all_kernel<<<1, 256, 0, stream>>>(
        sumM, sqM, sumL, sqL, sumH, sqH, Swsum, g_mid, be_mid, g_low, be_low,
        g_high, be_high, w_sa, b_sa, w_dy1, b_dy1, w_dy2, b_dy2, 1.0f / P,
        1.0f / Ph, hasLow, hasHigh, 1.0f / nterm[l], Am, Bm, Al, Bl, Ah, Bh,
        svec, dycoef);

    fused_apply_kernel<<<(NB * COUT * P) / 256, 256, 0, stream>>>(
        featM, featL, featH, Am, Bm, Al, Bl, Ah, Bh, svec, dycoef, outl, P, H,
        Hh, hasLow, hasHigh, 1.0f / nterm[l]);
  }
}